// Round 11
// baseline (276.939 us; speedup 1.0000x reference)
//
#include <hip/hip_runtime.h>

#define Nn 50000
#define Ee 800000

typedef _Float16 half8 __attribute__((ext_vector_type(8)));
typedef __fp16 fp16x2 __attribute__((ext_vector_type(2)));
typedef float floatx16 __attribute__((ext_vector_type(16)));

// ---- workspace layout (bytes) ----
#define SD_OFF      0                                    // int2[Ee] sorted (src,dst)
#define DEG_OFF     ((size_t)Ee * 8)                     // 6,400,000
#define OFF_OFF     (DEG_OFF + (size_t)Nn * 4)
#define BSUM_OFF    (OFF_OFF + (size_t)Nn * 4)
#define WT_OFF      (BSUM_OFF + 256)                     // 16B-aligned
#define WT_HALVES   21504
#define WU_OFF      (WT_OFF + (size_t)WT_HALVES * 2)     // Wu1^T f16 [64][128]
#define WU_HALVES   8192
#define Z16_OFF     (WU_OFF + (size_t)WU_HALVES * 2)
#define C4_OFF      (Z16_OFF + (size_t)Nn * 64 * 2)
#define TOTAL_WS    (C4_OFF + (size_t)Nn * 16)           // ~14 MB

// wt sub-offsets in GLOBAL packed table (halves)
#define WE1T 0
#define WE2T 1024
#define WM1T 5120
#define WM2T 17408

// LDS padded layout (halves): We1 packed(16), We2/Wm2 stride 72, Wm1 stride 200
#define SWE1 0
#define SWE2 1024
#define SWM1 5632          // 1024 + 64*72
#define SWM2 18432         // 5632 + 64*200
#define SWT_HALVES 23040   // 18432 + 64*72  -> 46080 B

// prep kernel grid partition
#define ZP_NB   1563
#define C4_NB   196
#define WT_NB   84
#define WU_NB   32
#define HI_NB   3125
#define PREP_NB (ZP_NB + C4_NB + WT_NB + WU_NB + HI_NB)

// edge grid: 25000 waves (32 edges each), 16 waves per 1024-thread block
#define EDGE_NB 1563

// ===========================================================================
// Fused prep: z->f16, cent->float4, edge-weight transpose/cvt, Wu1 transpose,
// dst histogram.
// ===========================================================================
__global__ __launch_bounds__(256) void prep_kernel(
    const float* __restrict__ z, const float* __restrict__ cent,
    const int* __restrict__ ei,
    const float* __restrict__ We1, const float* __restrict__ We2,
    const float* __restrict__ Wm1, const float* __restrict__ Wm2,
    const float* __restrict__ Wu1,
    _Float16* __restrict__ z16, float4* __restrict__ cent4,
    _Float16* __restrict__ wt, _Float16* __restrict__ wu,
    int* __restrict__ deg)
{
    const int b = blockIdx.x, tid = threadIdx.x;
    if (b < ZP_NB) {                                   // ---- z -> f16
        const int i8 = (b * 256 + tid) * 8;
        if (i8 < Nn * 64) {
            const float4 a4 = *(const float4*)(z + i8);
            const float4 b4 = *(const float4*)(z + i8 + 4);
            half8 hv;
            hv[0] = (_Float16)a4.x; hv[1] = (_Float16)a4.y;
            hv[2] = (_Float16)a4.z; hv[3] = (_Float16)a4.w;
            hv[4] = (_Float16)b4.x; hv[5] = (_Float16)b4.y;
            hv[6] = (_Float16)b4.z; hv[7] = (_Float16)b4.w;
            *(half8*)(z16 + i8) = hv;
        }
    } else if (b < ZP_NB + C4_NB) {                    // ---- cent -> float4
        const int n = (b - ZP_NB) * 256 + tid;
        if (n < Nn)
            cent4[n] = make_float4(cent[n * 3], cent[n * 3 + 1], cent[n * 3 + 2], 0.0f);
    } else if (b < ZP_NB + C4_NB + WT_NB) {            // ---- edge weights wt[n][k]=W[k][n]
        const int i = (b - ZP_NB - C4_NB) * 256 + tid;
        float v;
        if (i < 1024) {                      // We1t [64][16], K=3 zero-padded
            const int n = i >> 4, k = i & 15;
            v = (k < 3) ? We1[k * 64 + n] : 0.0f;
        } else if (i < 5120) {               // We2t [64][64]
            const int j = i - 1024, n = j >> 6, k = j & 63;
            v = We2[k * 64 + n];
        } else if (i < 17408) {              // Wm1t [64][192]
            const int j = i - 5120, n = j / 192, k = j - n * 192;
            v = Wm1[k * 64 + n];
        } else {                             // Wm2t [64][64]
            const int j = i - 17408, n = j >> 6, k = j & 63;
            v = Wm2[k * 64 + n];
        }
        wt[i] = (_Float16)v;
    } else if (b < ZP_NB + C4_NB + WT_NB + WU_NB) {    // ---- Wu1t [64][128]
        const int i = (b - ZP_NB - C4_NB - WT_NB) * 256 + tid;
        const int n = i >> 7, k = i & 127;
        wu[i] = (_Float16)Wu1[k * 64 + n];
    } else {                                           // ---- histogram of dst
        const int e = (b - ZP_NB - C4_NB - WT_NB - WU_NB) * 256 + tid;
        atomicAdd(&deg[ei[Ee + e]], 1);
    }
}

// ===========================================================================
// Exclusive scan of deg[Nn] -> off[Nn]
// ===========================================================================
#define SCAN_TILE 4096
#define SCAN_NBLK 13

__global__ __launch_bounds__(1024) void scan1_kernel(const int* __restrict__ deg,
                                                     int* __restrict__ off,
                                                     int* __restrict__ bsum) {
    __shared__ int wsum[16];
    const int tid = threadIdx.x;
    const int lane = tid & 63, wid = tid >> 6;
    const int base = blockIdx.x * SCAN_TILE + tid * 4;

    int v0 = (base + 0 < Nn) ? deg[base + 0] : 0;
    int v1 = (base + 1 < Nn) ? deg[base + 1] : 0;
    int v2 = (base + 2 < Nn) ? deg[base + 2] : 0;
    int v3 = (base + 3 < Nn) ? deg[base + 3] : 0;
    const int tsum = v0 + v1 + v2 + v3;

    int x = tsum;
    for (int s = 1; s < 64; s <<= 1) {
        int y = __shfl_up(x, s, 64);
        if (lane >= s) x += y;
    }
    if (lane == 63) wsum[wid] = x;
    __syncthreads();
    if (wid == 0) {
        int w = (lane < 16) ? wsum[lane] : 0;
        for (int s = 1; s < 16; s <<= 1) {
            int y = __shfl_up(w, s, 64);
            if (lane >= s) w += y;
        }
        if (lane < 16) wsum[lane] = w;
    }
    __syncthreads();
    const int wpre = wid ? wsum[wid - 1] : 0;
    const int tpre = wpre + (x - tsum);
    if (base + 0 < Nn) off[base + 0] = tpre;
    if (base + 1 < Nn) off[base + 1] = tpre + v0;
    if (base + 2 < Nn) off[base + 2] = tpre + v0 + v1;
    if (base + 3 < Nn) off[base + 3] = tpre + v0 + v1 + v2;
    if (tid == 1023) bsum[blockIdx.x] = wsum[15];
}

__global__ __launch_bounds__(1024) void scan3_kernel(int* __restrict__ off,
                                                     const int* __restrict__ bsum) {
    int add = 0;
    for (int i = 0; i < blockIdx.x; ++i) add += bsum[i];
    const int base = blockIdx.x * SCAN_TILE + threadIdx.x * 4;
    if (base + 0 < Nn) off[base + 0] += add;
    if (base + 1 < Nn) off[base + 1] += add;
    if (base + 2 < Nn) off[base + 2] += add;
    if (base + 3 < Nn) off[base + 3] += add;
}

// off[dst] advanced to end pointer (sums zeroing moved to hipMemsetAsync).
__global__ __launch_bounds__(256) void fill_kernel(const int* __restrict__ ei,
                                                   int* __restrict__ off,
                                                   int2* __restrict__ sd) {
    const int e = blockIdx.x * 256 + threadIdx.x;
    const int s = ei[e];
    const int d = ei[Ee + e];
    const int pos = atomicAdd(&off[d], 1);
    sd[pos] = make_int2(s, d);
}

// ===========================================================================
// MFMA helpers (proven R8/R9 machinery)
//   A/B frag (32x32x16, isomorphic): lane&31 = non-K dim, regs = 8 contig k
//   C/D: row=(r&3)+8*(r>>2)+4*(lane>>5), col=lane&31
// ===========================================================================
__device__ __forceinline__ floatx16 mfma16(half8 a, half8 b, floatx16 c) {
    return __builtin_amdgcn_mfma_f32_32x32x16_f16(a, b, c, 0, 0, 0);
}

__device__ __forceinline__ half8 shx32(half8 v) {
    union { half8 h; int i[4]; } u;
    u.h = v;
    #pragma unroll
    for (int q = 0; q < 4; ++q) u.i[q] = __shfl_xor(u.i[q], 32, 64);
    return u.h;
}

__device__ __forceinline__ unsigned pkrtz(float a, float b) {
    union { fp16x2 h; unsigned u; } c;
    c.h = __builtin_amdgcn_cvt_pkrtz(a, b);
    return c.u;
}

// Pack transposed-layer acc (+bias, relu) into 8 dwords (regs 2q,2q+1 -> dw q).
__device__ __forceinline__ void pack_acc(const floatx16& acc, const float* bias,
                                         int boff, int kh, unsigned* pk) {
    #pragma unroll
    for (int q = 0; q < 8; ++q) {
        const int r0 = 2 * q, r1 = 2 * q + 1;
        const int f0 = (r0 & 3) + 8 * (r0 >> 2);
        const int f1 = (r1 & 3) + 8 * (r1 >> 2);
        const float ba = kh ? bias[boff + f0 + 4] : bias[boff + f0];
        const float bb = kh ? bias[boff + f1 + 4] : bias[boff + f1];
        pk[q] = pkrtz(fmaxf(acc[r0] + ba, 0.0f), fmaxf(acc[r1] + bb, 0.0f));
    }
}

// Assemble act fragment for K-step (s&1) from packed dwords via one
// half-exchange with the partner lane (er, kh^1).
__device__ __forceinline__ half8 frag_from_pk(const unsigned* pk, int s1, int kh) {
    const unsigned lo0 = pk[4 * s1], lo1 = pk[4 * s1 + 1];
    const unsigned hi0 = pk[4 * s1 + 2], hi1 = pk[4 * s1 + 3];
    const unsigned X0 = kh ? lo0 : hi0;
    const unsigned X1 = kh ? lo1 : hi1;
    const unsigned r0 = (unsigned)__shfl_xor((int)X0, 32, 64);
    const unsigned r1 = (unsigned)__shfl_xor((int)X1, 32, 64);
    union { half8 h; unsigned u[4]; } f;
    f.u[0] = kh ? r0 : lo0;
    f.u[1] = kh ? r1 : lo1;
    f.u[2] = kh ? hi0 : r0;
    f.u[3] = kh ? hi1 : r1;
    return f.h;
}

// ===========================================================================
// Edge kernel: 1024-thread blocks -> 16 waves share one 46KB staged table;
// 2 blocks/CU hits the 2048-thread cap = 32 waves/CU (was ~12 in flight).
// Last block has dead waves (25000 waves over 1563 blocks) -> wave-uniform
// `live` guard after the barrier.
// ===========================================================================
__global__ __launch_bounds__(1024) void edge_mfma_kernel(
    const _Float16* __restrict__ z16, const float4* __restrict__ cent4,
    const int2* __restrict__ sd,
    const _Float16* __restrict__ wt,
    const float* __restrict__ be1, const float* __restrict__ be2,
    const float* __restrict__ bm1, const float* __restrict__ bm2,
    float* __restrict__ sums)
{
    __shared__ _Float16 swt[SWT_HALVES];   // 46080 B
    const int tid = threadIdx.x;
    const int wid = tid >> 6, lane = tid & 63;
    const int er = lane & 31;
    const int kh = lane >> 5;        // 0: src-row holder, 1: dst-row holder
    const int tile = (blockIdx.x * 16 + wid) * 32;
    const bool live = (tile < Ee);

    // ---- stage weight table: global (packed) -> LDS (bank-padded) ----
    {
        const half8* __restrict__ g = (const half8*)wt;
        for (int i = tid; i < 2688; i += 1024) {
            const half8 v = g[i];
            int dst;
            if (i < 128) {                         // We1 packed (16/row)
                dst = SWE1 + i * 8;
            } else if (i < 640) {                  // We2: 8 chunks/row -> stride 72
                const int j = i - 128;
                dst = SWE2 + (j >> 3) * 72 + (j & 7) * 8;
            } else if (i < 2176) {                 // Wm1: 24 chunks/row -> stride 200
                const int j = i - 640;
                dst = SWM1 + (j / 24) * 200 + (j % 24) * 8;
            } else {                               // Wm2: stride 72
                const int j = i - 2176;
                dst = SWM2 + (j >> 3) * 72 + (j & 7) * 8;
            }
            *(half8*)(swt + dst) = v;
        }
    }

    const int p = live ? (tile + er) : 0;
    const int2 e2i = sd[p];
    const int row = kh ? e2i.y : e2i.x;

    // ---- z row -> registers (8 x half8) ----
    half8 zreg[8];
    const half8* __restrict__ zr = (const half8*)(z16 + (size_t)row * 64);
    #pragma unroll
    for (int c = 0; c < 8; ++c) zreg[c] = zr[c];

    // ---- centroid delta (src vals in lanes 0-31, dst in 32-63) ----
    const float4 cv = cent4[row];
    const float d0 = __shfl(cv.x, er + 32, 64) - __shfl(cv.x, er, 64);
    const float d1 = __shfl(cv.y, er + 32, 64) - __shfl(cv.y, er, 64);
    const float d2 = __shfl(cv.z, er + 32, 64) - __shfl(cv.z, er, 64);

    __syncthreads();   // weights staged (all threads reach this)
    if (!live) return;

    // ---- e1' = (delta @ We1)^T : K=16 (3 real), transposed orientation ----
    half8 bdel;
    #pragma unroll
    for (int j = 0; j < 8; ++j) bdel[j] = (_Float16)0.0f;
    if (kh == 0) { bdel[0] = (_Float16)d0; bdel[1] = (_Float16)d1; bdel[2] = (_Float16)d2; }

    unsigned pk0[8], pk1[8];
    {
        floatx16 A0, A1;
        #pragma unroll
        for (int r = 0; r < 16; ++r) { A0[r] = 0.0f; A1[r] = 0.0f; }
        const half8 w0 = *(const half8*)(swt + SWE1 + er * 16 + kh * 8);
        const half8 w1 = *(const half8*)(swt + SWE1 + (32 + er) * 16 + kh * 8);
        A0 = mfma16(w0, bdel, A0);
        A1 = mfma16(w1, bdel, A1);
        pack_acc(A0, be1, 0, kh, pk0);    // relu(e1+be1), f16-packed
        pack_acc(A1, be1, 32, kh, pk1);
    }

    // ---- e2' = (e1 @ We2)^T : K=64 ----
    unsigned qk0[8], qk1[8];
    {
        floatx16 B0, B1;
        #pragma unroll
        for (int r = 0; r < 16; ++r) { B0[r] = 0.0f; B1[r] = 0.0f; }
        #pragma unroll
        for (int s = 0; s < 4; ++s) {
            const half8 act = frag_from_pk((s < 2) ? pk0 : pk1, s & 1, kh);
            const half8 w0 = *(const half8*)(swt + SWE2 + er * 72 + s * 16 + kh * 8);
            const half8 w1 = *(const half8*)(swt + SWE2 + (32 + er) * 72 + s * 16 + kh * 8);
            B0 = mfma16(w0, act, B0);
            B1 = mfma16(w1, act, B1);
        }
        pack_acc(B0, be2, 0, kh, qk0);
        pack_acc(B1, be2, 32, kh, qk1);
    }

    // ---- h1' = ([z_src|z_dst|e2] @ Wm1)^T : K=192 ----
    unsigned rk0[8], rk1[8];
    {
        floatx16 C0, C1;
        #pragma unroll
        for (int r = 0; r < 16; ++r) { C0[r] = 0.0f; C1[r] = 0.0f; }
        // z_src phase (k 0..63)
        #pragma unroll
        for (int s = 0; s < 4; ++s) {
            const half8 recv = shx32(zreg[2 * s + 1]);
            const half8 act = kh ? recv : zreg[2 * s];
            const half8 w0 = *(const half8*)(swt + SWM1 + er * 200 + s * 16 + kh * 8);
            const half8 w1 = *(const half8*)(swt + SWM1 + (32 + er) * 200 + s * 16 + kh * 8);
            C0 = mfma16(w0, act, C0);
            C1 = mfma16(w1, act, C1);
        }
        // z_dst phase (k 64..127)
        #pragma unroll
        for (int s = 0; s < 4; ++s) {
            const half8 recv = shx32(zreg[2 * s]);
            const half8 act = kh ? zreg[2 * s + 1] : recv;
            const half8 w0 = *(const half8*)(swt + SWM1 + er * 200 + 64 + s * 16 + kh * 8);
            const half8 w1 = *(const half8*)(swt + SWM1 + (32 + er) * 200 + 64 + s * 16 + kh * 8);
            C0 = mfma16(w0, act, C0);
            C1 = mfma16(w1, act, C1);
        }
        // e2 phase (k 128..191)
        #pragma unroll
        for (int s = 0; s < 4; ++s) {
            const half8 act = frag_from_pk((s < 2) ? qk0 : qk1, s & 1, kh);
            const half8 w0 = *(const half8*)(swt + SWM1 + er * 200 + 128 + s * 16 + kh * 8);
            const half8 w1 = *(const half8*)(swt + SWM1 + (32 + er) * 200 + 128 + s * 16 + kh * 8);
            C0 = mfma16(w0, act, C0);
            C1 = mfma16(w1, act, C1);
        }
        pack_acc(C0, bm1, 0, kh, rk0);
        pack_acc(C1, bm1, 32, kh, rk1);
    }

    // ---- m = h1 @ Wm2 + bm2 : NORMAL orientation (edges in C-rows) ----
    floatx16 M0, M1;
    {
        const float bias0 = bm2[er], bias1 = bm2[32 + er];
        #pragma unroll
        for (int r = 0; r < 16; ++r) { M0[r] = bias0; M1[r] = bias1; }
        #pragma unroll
        for (int s = 0; s < 4; ++s) {
            const half8 act = frag_from_pk((s < 2) ? rk0 : rk1, s & 1, kh);  // A-frag
            const half8 w0 = *(const half8*)(swt + SWM2 + er * 72 + s * 16 + kh * 8);
            const half8 w1 = *(const half8*)(swt + SWM2 + (32 + er) * 72 + s * 16 + kh * 8);
            M0 = mfma16(act, w0, M0);
            M1 = mfma16(act, w1, M1);
        }
    }

    // ---- segmented (by dst) reduction + coalesced atomics ----
    const int dprev = __shfl(e2i.y, (er + 31) & 31, 64);
    const bool boundary = (er == 0) || (e2i.y != dprev);
    unsigned int m32 = (unsigned int)__ballot(boundary);

    while (m32) {
        const int a = __builtin_ctz(m32);
        m32 &= m32 - 1;
        const int b = m32 ? __builtin_ctz(m32) : 32;
        float p0 = 0.0f, p1 = 0.0f;
        #pragma unroll
        for (int r = 0; r < 16; ++r) {
            const int rrow = (r & 3) + 8 * (r >> 2) + 4 * kh;
            if (rrow >= a && rrow < b) { p0 += M0[r]; p1 += M1[r]; }
        }
        p0 += __shfl_xor(p0, 32, 64);
        p1 += __shfl_xor(p1, 32, 64);
        const float val = kh ? p1 : p0;          // lane l -> feature l
        const int dseg = __shfl(e2i.y, a, 64);
        atomicAdd(&sums[(size_t)dseg * 64 + lane], val);
    }
}

// ===========================================================================
// Node kernel (MFMA): wave = 32 nodes. kh=0 lane holds z row, kh=1 holds
// M row (sums*1/deg). K=128 via the same shfl_xor half-exchange. Wu1t staged
// in LDS. Output: nodes in C-rows, features in lanes -> coalesced stores.
// ===========================================================================
__global__ __launch_bounds__(256) void node_mfma_kernel(
    const float* __restrict__ z, const _Float16* __restrict__ wu1t,
    const float* __restrict__ bu1, const int* __restrict__ deg,
    float* __restrict__ out)
{
    __shared__ _Float16 swu[64 * 136];   // 17408 B
    const int tid = threadIdx.x;
    const int wid = tid >> 6, lane = tid & 63;
    const int er = lane & 31, kh = lane >> 5;
    const int tile = (blockIdx.x * 4 + wid) * 32;
    const int node = tile + er;

    // stage Wu1t [64][128] -> LDS stride 136
    {
        const half8* __restrict__ g = (const half8*)wu1t;   // 1024 chunks
        for (int i = tid; i < 1024; i += 256) {
            const half8 v = g[i];
            const int n = i >> 4, c = i & 15;
            *(half8*)(swu + n * 136 + c * 8) = v;
        }
    }

    const int nclamp = (node < Nn) ? node : (Nn - 1);
    const int dn = deg[nclamp];
    const float scale = kh ? (1.0f / fmaxf((float)dn, 1.0f)) : 1.0f;
    const float* __restrict__ rowp = kh ? (out + (size_t)nclamp * 64)
                                        : (z + (size_t)nclamp * 64);
    half8 vreg[8];
    #pragma unroll
    for (int c = 0; c < 8; ++c) {
        const float4 a4 = *(const float4*)(rowp + c * 8);
        const float4 b4 = *(const float4*)(rowp + c * 8 + 4);
        union { half8 h; unsigned u[4]; } hv;
        hv.u[0] = pkrtz(a4.x * scale, a4.y * scale);
        hv.u[1] = pkrtz(a4.z * scale, a4.w * scale);
        hv.u[2] = pkrtz(b4.x * scale, b4.y * scale);
        hv.u[3] = pkrtz(b4.z * scale, b4.w * scale);
        vreg[c] = hv.h;
    }

    __syncthreads();

    floatx16 M0, M1;
    const float bias0 = bu1[er], bias1 = bu1[32 + er];
    #pragma unroll
    for (int r = 0; r < 16; ++r) { M0[r] = bias0; M1[r] = bias1; }
    // z phase (k 0..63): z row held by kh=0 lane
    #pragma unroll
    for (int s = 0; s < 4; ++s) {
        const half8 recv = shx32(vreg[2 * s + 1]);
        const half8 act = kh ? recv : vreg[2 * s];
        const half8 w0 = *(const half8*)(swu + er * 136 + s * 16 + kh * 8);
        const half8 w1 = *(const half8*)(swu + (32 + er) * 136 + s * 16 + kh * 8);
        M0 = mfma16(act, w0, M0);
        M1 = mfma16(act, w1, M1);
    }
    // M phase (k 64..127): M row held by kh=1 lane
    #pragma unroll
    for (int s = 0; s < 4; ++s) {
        const half8 recv = shx32(vreg[2 * s]);
        const half8 act = kh ? vreg[2 * s + 1] : recv;
        const half8 w0 = *(const half8*)(swu + er * 136 + 64 + s * 16 + kh * 8);
        const half8 w1 = *(const half8*)(swu + (32 + er) * 136 + 64 + s * 16 + kh * 8);
        M0 = mfma16(act, w0, M0);
        M1 = mfma16(act, w1, M1);
    }

    // all reads of out rows happened above (in-order per wave); safe to store
    #pragma unroll
    for (int r = 0; r < 16; ++r) {
        const int rrow = (r & 3) + 8 * (r >> 2) + 4 * kh;
        const int nrow = tile + rrow;
        if (nrow < Nn) {
            out[(size_t)nrow * 64 + er]      = fmaxf(M0[r], 0.0f);
            out[(size_t)nrow * 64 + 32 + er] = fmaxf(M1[r], 0.0f);
        }
    }
}

// ===========================================================================
// Fallback (atomic, fp32) — only if ws_size too small. Known-correct (R1).
// ===========================================================================
__global__ __launch_bounds__(256) void edge_kernel_atomic(
    const float* __restrict__ z, const float* __restrict__ cent,
    const int* __restrict__ ei,
    const float* __restrict__ We1, const float* __restrict__ be1,
    const float* __restrict__ We2, const float* __restrict__ be2,
    const float* __restrict__ Wm1, const float* __restrict__ bm1,
    const float* __restrict__ Wm2, const float* __restrict__ bm2,
    float* __restrict__ sums, float* __restrict__ cnt)
{
    __shared__ float buf[64][256];
    const int tid = threadIdx.x;
    const int e = blockIdx.x * 256 + tid;
    const int src = ei[e];
    const int dst = ei[Ee + e];
    const float d0 = cent[dst * 3 + 0] - cent[src * 3 + 0];
    const float d1 = cent[dst * 3 + 1] - cent[src * 3 + 1];
    const float d2 = cent[dst * 3 + 2] - cent[src * 3 + 2];
    for (int j = 0; j < 64; ++j) {
        float v = fmaf(d0, We1[j], fmaf(d1, We1[64 + j], fmaf(d2, We1[128 + j], be1[j])));
        buf[j][tid] = fmaxf(v, 0.0f);
    }
    float acc[64];
    #pragma unroll
    for (int j = 0; j < 64; ++j) acc[j] = be2[j];
    for (int k = 0; k < 64; ++k) {
        const float ek = buf[k][tid];
        const float* wrow = We2 + k * 64;
        #pragma unroll
        for (int j = 0; j < 64; ++j) acc[j] = fmaf(ek, wrow[j], acc[j]);
    }
    #pragma unroll
    for (int j = 0; j < 64; ++j) buf[j][tid] = fmaxf(acc[j], 0.0f);
    #pragma unroll
    for (int j = 0; j < 64; ++j) acc[j] = bm1[j];
    const float* zs = z + src * 64;
    for (int k = 0; k < 64; ++k) {
        const float hk = zs[k];
        const float* wrow = Wm1 + k * 64;
        #pragma unroll
        for (int j = 0; j < 64; ++j) acc[j] = fmaf(hk, wrow[j], acc[j]);
    }
    const float* zd = z + dst * 64;
    for (int k = 0; k < 64; ++k) {
        const float hk = zd[k];
        const float* wrow = Wm1 + (64 + k) * 64;
        #pragma unroll
        for (int j = 0; j < 64; ++j) acc[j] = fmaf(hk, wrow[j], acc[j]);
    }
    for (int k = 0; k < 64; ++k) {
        const float hk = buf[k][tid];
        const float* wrow = Wm1 + (128 + k) * 64;
        #pragma unroll
        for (int j = 0; j < 64; ++j) acc[j] = fmaf(hk, wrow[j], acc[j]);
    }
    #pragma unroll
    for (int j = 0; j < 64; ++j) buf[j][tid] = fmaxf(acc[j], 0.0f);
    #pragma unroll
    for (int j = 0; j < 64; ++j) acc[j] = bm2[j];
    for (int k = 0; k < 64; ++k) {
        const float hk = buf[k][tid];
        const float* wrow = Wm2 + k * 64;
        #pragma unroll
        for (int j = 0; j < 64; ++j) acc[j] = fmaf(hk, wrow[j], acc[j]);
    }
    float* srow = sums + dst * 64;
    #pragma unroll
    for (int j = 0; j < 64; ++j) atomicAdd(&srow[j], acc[j]);
    atomicAdd(&cnt[dst], 1.0f);
}

__global__ __launch_bounds__(256) void node_kernel_atomic(
    const float* __restrict__ z,
    const float* __restrict__ Wu1, const float* __restrict__ bu1,
    float* __restrict__ out, const float* __restrict__ cnt)
{
    const int node = (blockIdx.x * 256 + threadIdx.x) >> 6;
    const int j = threadIdx.x & 63;
    const int base = node * 64;
    const float inv = 1.0f / fmaxf(cnt[node], 1.0f);
    const float zj = z[base + j];
    const float mj = out[base + j] * inv;
    float a = bu1[j];
    for (int k = 0; k < 64; ++k)
        a = fmaf(__shfl(zj, k, 64), Wu1[k * 64 + j], a);
    for (int k = 0; k < 64; ++k)
        a = fmaf(__shfl(mj, k, 64), Wu1[(64 + k) * 64 + j], a);
    out[base + j] = fmaxf(a, 0.0f);
}

extern "C" void kernel_launch(void* const* d_in, const int* in_sizes, int n_in,
                              void* d_out, int out_size, void* d_ws, size_t ws_size,
                              hipStream_t stream) {
    const float* z    = (const float*)d_in[0];
    const float* cent = (const float*)d_in[1];
    const int*   ei   = (const int*)d_in[2];
    const float* We1  = (const float*)d_in[3];
    const float* be1  = (const float*)d_in[4];
    const float* We2  = (const float*)d_in[5];
    const float* be2  = (const float*)d_in[6];
    const float* Wm1  = (const float*)d_in[7];
    const float* bm1  = (const float*)d_in[8];
    const float* Wm2  = (const float*)d_in[9];
    const float* bm2  = (const float*)d_in[10];
    const float* Wu1  = (const float*)d_in[11];
    const float* bu1  = (const float*)d_in[12];
    float* out = (float*)d_out;

    if (ws_size >= TOTAL_WS) {
        int2* sd   = (int2*)((char*)d_ws + SD_OFF);
        int* deg   = (int*)((char*)d_ws + DEG_OFF);
        int* off   = (int*)((char*)d_ws + OFF_OFF);
        int* bsum  = (int*)((char*)d_ws + BSUM_OFF);
        _Float16* wt  = (_Float16*)((char*)d_ws + WT_OFF);
        _Float16* wu  = (_Float16*)((char*)d_ws + WU_OFF);
        _Float16* z16 = (_Float16*)((char*)d_ws + Z16_OFF);
        float4* cent4 = (float4*)((char*)d_ws + C4_OFF);

        hipMemsetAsync(deg, 0, Nn * sizeof(int), stream);
        hipMemsetAsync(out, 0, (size_t)Nn * 64 * sizeof(float), stream);
        prep_kernel<<<PREP_NB, 256, 0, stream>>>(z, cent, ei, We1, We2, Wm1, Wm2,
                                                 Wu1, z16, cent4, wt, wu, deg);
        scan1_kernel<<<SCAN_NBLK, 1024, 0, stream>>>(deg, off, bsum);
        scan3_kernel<<<SCAN_NBLK, 1024, 0, stream>>>(off, bsum);
        fill_kernel<<<Ee / 256, 256, 0, stream>>>(ei, off, sd);
        edge_mfma_kernel<<<EDGE_NB, 1024, 0, stream>>>(z16, cent4, sd, wt,
            be1, be2, bm1, bm2, out);
        node_mfma_kernel<<<(Nn + 127) / 128, 256, 0, stream>>>(z, wu, bu1, deg, out);
    } else {
        float* cnt = (float*)d_ws;
        hipMemsetAsync(out, 0, (size_t)Nn * 64 * sizeof(float), stream);
        hipMemsetAsync(cnt, 0, (size_t)Nn * sizeof(float), stream);
        edge_kernel_atomic<<<Ee / 256, 256, 0, stream>>>(z, cent, ei,
            We1, be1, We2, be2, Wm1, bm1, Wm2, bm2, out, cnt);
        node_kernel_atomic<<<Nn / 4, 256, 0, stream>>>(z, Wu1, bu1, out, cnt);
    }
}

// Round 12
// 246.205 us; speedup vs baseline: 1.1248x; 1.1248x over previous
//
#include <hip/hip_runtime.h>

#define Nn 50000
#define Ee 800000

typedef _Float16 half8 __attribute__((ext_vector_type(8)));
typedef __fp16 fp16x2 __attribute__((ext_vector_type(2)));
typedef float floatx16 __attribute__((ext_vector_type(16)));

// ---- workspace layout (bytes) ----
#define SD_OFF      0                                    // int2[Ee]
#define DEG_OFF     (SD_OFF + (size_t)Ee * 8)
#define OFF_OFF     (DEG_OFF + (size_t)Nn * 4)
#define BSUM_OFF    (OFF_OFF + (size_t)Nn * 4)
#define RANK_OFF    (BSUM_OFF + 256)                     // int[Ee]
#define WT_OFF      (RANK_OFF + (size_t)Ee * 4)
#define WT_HALVES   25600   // We1t 1024 | We2t 4096 | Wm1t 12288 | Wm2t 4096 | Wm1c 4096
#define WU_OFF      (WT_OFF + (size_t)WT_HALVES * 2)
#define WU_HALVES   8192
#define Z16_OFF     (WU_OFF + (size_t)WU_HALVES * 2)
#define PQ_OFF      (Z16_OFF + (size_t)Nn * 64 * 2)      // PQp f16 [Nn][128]
#define C4_OFF      (PQ_OFF + (size_t)Nn * 128 * 2)
#define TOTAL_WS    (C4_OFF + (size_t)Nn * 16)           // ~33 MB

// wt sub-offsets in GLOBAL packed table (halves)
#define WE1T 0
#define WE2T 1024
#define WM1T 5120
#define WM2T 17408
#define WM1C 21504   // compact e2-block of Wm1: [64][64]

// LDS padded layout (halves)
#define SWE1 0
#define SWE2 1024          // stride 72
#define SWM1C 5632         // stride 72
#define SWM2 10240         // stride 72
#define SWT_HALVES 14848   // 29696 B

// prep kernel grid partition
#define ZP_NB   1563
#define C4_NB   196
#define WT_NB   100
#define WU_NB   32
#define HI_NB   3125
#define PREP_NB (ZP_NB + C4_NB + WT_NB + WU_NB + HI_NB)

// ===========================================================================
// Fused prep: z->f16, cent->float4, weight tables, Wu1t, histogram+rank.
// ===========================================================================
__global__ __launch_bounds__(256) void prep_kernel(
    const float* __restrict__ z, const float* __restrict__ cent,
    const int* __restrict__ ei,
    const float* __restrict__ We1, const float* __restrict__ We2,
    const float* __restrict__ Wm1, const float* __restrict__ Wm2,
    const float* __restrict__ Wu1,
    _Float16* __restrict__ z16, float4* __restrict__ cent4,
    _Float16* __restrict__ wt, _Float16* __restrict__ wu,
    int* __restrict__ deg, int* __restrict__ rank)
{
    const int b = blockIdx.x, tid = threadIdx.x;
    if (b < ZP_NB) {                                   // ---- z -> f16
        const int i8 = (b * 256 + tid) * 8;
        if (i8 < Nn * 64) {
            const float4 a4 = *(const float4*)(z + i8);
            const float4 b4 = *(const float4*)(z + i8 + 4);
            half8 hv;
            hv[0] = (_Float16)a4.x; hv[1] = (_Float16)a4.y;
            hv[2] = (_Float16)a4.z; hv[3] = (_Float16)a4.w;
            hv[4] = (_Float16)b4.x; hv[5] = (_Float16)b4.y;
            hv[6] = (_Float16)b4.z; hv[7] = (_Float16)b4.w;
            *(half8*)(z16 + i8) = hv;
        }
    } else if (b < ZP_NB + C4_NB) {                    // ---- cent -> float4
        const int n = (b - ZP_NB) * 256 + tid;
        if (n < Nn)
            cent4[n] = make_float4(cent[n * 3], cent[n * 3 + 1], cent[n * 3 + 2], 0.0f);
    } else if (b < ZP_NB + C4_NB + WT_NB) {            // ---- weight tables
        const int i = (b - ZP_NB - C4_NB) * 256 + tid;
        if (i < 25600) {
            float v;
            if (i < 1024) {                      // We1t [64][16], K=3 zero-padded
                const int n = i >> 4, k = i & 15;
                v = (k < 3) ? We1[k * 64 + n] : 0.0f;
            } else if (i < 5120) {               // We2t [64][64]
                const int j = i - 1024, n = j >> 6, k = j & 63;
                v = We2[k * 64 + n];
            } else if (i < 17408) {              // Wm1t [64][192]
                const int j = i - 5120, n = j / 192, k = j - n * 192;
                v = Wm1[k * 64 + n];
            } else if (i < 21504) {              // Wm2t [64][64]
                const int j = i - 17408, n = j >> 6, k = j & 63;
                v = Wm2[k * 64 + n];
            } else {                             // Wm1c [64][64] (k 128..191)
                const int j = i - 21504, n = j >> 6, k = j & 63;
                v = Wm1[(128 + k) * 64 + n];
            }
            wt[i] = (_Float16)v;
        }
    } else if (b < ZP_NB + C4_NB + WT_NB + WU_NB) {    // ---- Wu1t [64][128]
        const int i = (b - ZP_NB - C4_NB - WT_NB) * 256 + tid;
        const int n = i >> 7, k = i & 127;
        wu[i] = (_Float16)Wu1[k * 64 + n];
    } else {                                           // ---- histogram + rank
        const int e = (b - ZP_NB - C4_NB - WT_NB - WU_NB) * 256 + tid;
        rank[e] = atomicAdd(&deg[ei[Ee + e]], 1);
    }
}

// ===========================================================================
// Exclusive scan of deg[Nn] -> off[Nn]
// ===========================================================================
#define SCAN_TILE 4096
#define SCAN_NBLK 13

__global__ __launch_bounds__(1024) void scan1_kernel(const int* __restrict__ deg,
                                                     int* __restrict__ off,
                                                     int* __restrict__ bsum) {
    __shared__ int wsum[16];
    const int tid = threadIdx.x;
    const int lane = tid & 63, wid = tid >> 6;
    const int base = blockIdx.x * SCAN_TILE + tid * 4;

    int v0 = (base + 0 < Nn) ? deg[base + 0] : 0;
    int v1 = (base + 1 < Nn) ? deg[base + 1] : 0;
    int v2 = (base + 2 < Nn) ? deg[base + 2] : 0;
    int v3 = (base + 3 < Nn) ? deg[base + 3] : 0;
    const int tsum = v0 + v1 + v2 + v3;

    int x = tsum;
    for (int s = 1; s < 64; s <<= 1) {
        int y = __shfl_up(x, s, 64);
        if (lane >= s) x += y;
    }
    if (lane == 63) wsum[wid] = x;
    __syncthreads();
    if (wid == 0) {
        int w = (lane < 16) ? wsum[lane] : 0;
        for (int s = 1; s < 16; s <<= 1) {
            int y = __shfl_up(w, s, 64);
            if (lane >= s) w += y;
        }
        if (lane < 16) wsum[lane] = w;
    }
    __syncthreads();
    const int wpre = wid ? wsum[wid - 1] : 0;
    const int tpre = wpre + (x - tsum);
    if (base + 0 < Nn) off[base + 0] = tpre;
    if (base + 1 < Nn) off[base + 1] = tpre + v0;
    if (base + 2 < Nn) off[base + 2] = tpre + v0 + v1;
    if (base + 3 < Nn) off[base + 3] = tpre + v0 + v1 + v2;
    if (tid == 1023) bsum[blockIdx.x] = wsum[15];
}

__global__ __launch_bounds__(1024) void scan3_kernel(int* __restrict__ off,
                                                     const int* __restrict__ bsum) {
    int add = 0;
    for (int i = 0; i < blockIdx.x; ++i) add += bsum[i];
    const int base = blockIdx.x * SCAN_TILE + threadIdx.x * 4;
    if (base + 0 < Nn) off[base + 0] += add;
    if (base + 1 < Nn) off[base + 1] += add;
    if (base + 2 < Nn) off[base + 2] += add;
    if (base + 3 < Nn) off[base + 3] += add;
}

// Atomic-free scatter: pos = off[d] + rank[e]. Also zeroes sums (d_out).
__global__ __launch_bounds__(256) void fill_kernel(const int* __restrict__ ei,
                                                   const int* __restrict__ off,
                                                   const int* __restrict__ rank,
                                                   int2* __restrict__ sd,
                                                   float4* __restrict__ sums4) {
    const int e = blockIdx.x * 256 + threadIdx.x;
    const int s = ei[e];
    const int d = ei[Ee + e];
    sums4[e] = make_float4(0.f, 0.f, 0.f, 0.f);   // Ee float4 = Nn*64 floats exact
    sd[off[d] + rank[e]] = make_int2(s, d);
}

// ===========================================================================
// MFMA helpers
//   A/B frag (32x32x16, isomorphic): lane&31 = non-K dim, regs = 8 contig k
//   C/D: row=(r&3)+8*(r>>2)+4*(lane>>5), col=lane&31
// ===========================================================================
__device__ __forceinline__ floatx16 mfma16(half8 a, half8 b, floatx16 c) {
    return __builtin_amdgcn_mfma_f32_32x32x16_f16(a, b, c, 0, 0, 0);
}

__device__ __forceinline__ unsigned pkrtz(float a, float b) {
    union { fp16x2 h; unsigned u; } c;
    c.h = __builtin_amdgcn_cvt_pkrtz(a, b);
    return c.u;
}

__device__ __forceinline__ void pack_acc(const floatx16& acc, const float* bias,
                                         int boff, int kh, unsigned* pk) {
    #pragma unroll
    for (int q = 0; q < 8; ++q) {
        const int r0 = 2 * q, r1 = 2 * q + 1;
        const int f0 = (r0 & 3) + 8 * (r0 >> 2);
        const int f1 = (r1 & 3) + 8 * (r1 >> 2);
        const float ba = kh ? bias[boff + f0 + 4] : bias[boff + f0];
        const float bb = kh ? bias[boff + f1 + 4] : bias[boff + f1];
        pk[q] = pkrtz(fmaxf(acc[r0] + ba, 0.0f), fmaxf(acc[r1] + bb, 0.0f));
    }
}

__device__ __forceinline__ void pack_acc_nb(const floatx16& acc, unsigned* pk) {
    #pragma unroll
    for (int q = 0; q < 8; ++q)
        pk[q] = pkrtz(fmaxf(acc[2 * q], 0.0f), fmaxf(acc[2 * q + 1], 0.0f));
}

__device__ __forceinline__ half8 frag_from_pk(const unsigned* pk, int s1, int kh) {
    const unsigned lo0 = pk[4 * s1], lo1 = pk[4 * s1 + 1];
    const unsigned hi0 = pk[4 * s1 + 2], hi1 = pk[4 * s1 + 3];
    const unsigned X0 = kh ? lo0 : hi0;
    const unsigned X1 = kh ? lo1 : hi1;
    const unsigned r0 = (unsigned)__shfl_xor((int)X0, 32, 64);
    const unsigned r1 = (unsigned)__shfl_xor((int)X1, 32, 64);
    union { half8 h; unsigned u[4]; } f;
    f.u[0] = kh ? r0 : lo0;
    f.u[1] = kh ? r1 : lo1;
    f.u[2] = kh ? hi0 : r0;
    f.u[3] = kh ? hi1 : r1;
    return f.h;
}

// ===========================================================================
// PQ kernel: per-node P = z@Wm1[0:64] + bm1, Q = z@Wm1[64:128], f16, stored
// in C-fragment-permuted layout: PQp[n][kh*32 + a*16 + r] = P[n][fsel],
// fsel = (r&3)+8*(r>>2)+4*kh+32*a; Q at +64. Normal-orientation MFMA,
// wave = 32 nodes (structure = final-m layer / node kernel).
// ===========================================================================
__global__ __launch_bounds__(256) void pq_kernel(
    const _Float16* __restrict__ z16, const _Float16* __restrict__ wt,
    const float* __restrict__ bm1, _Float16* __restrict__ pq)
{
    const int tid = threadIdx.x;
    const int wid = tid >> 6, lane = tid & 63;
    const int er = lane & 31, kh = lane >> 5;
    const int tile = (blockIdx.x * 4 + wid) * 32;
    const int nclamp = (tile + er < Nn) ? (tile + er) : (Nn - 1);

    const half8* __restrict__ zr = (const half8*)(z16 + (size_t)nclamp * 64);
    half8 a[4];
    #pragma unroll
    for (int s = 0; s < 4; ++s) a[s] = zr[2 * s + kh];   // A[n][s*16+kh*8+j]

    const _Float16* __restrict__ wm1t = wt + WM1T;
    floatx16 P0, P1, Q0, Q1;
    const float b0 = bm1[er], b1 = bm1[32 + er];
    #pragma unroll
    for (int r = 0; r < 16; ++r) { P0[r] = b0; P1[r] = b1; Q0[r] = 0.f; Q1[r] = 0.f; }

    #pragma unroll
    for (int s = 0; s < 4; ++s) {
        const half8 wp0 = *(const half8*)(wm1t + er * 192 + s * 16 + kh * 8);
        const half8 wp1 = *(const half8*)(wm1t + (32 + er) * 192 + s * 16 + kh * 8);
        const half8 wq0 = *(const half8*)(wm1t + er * 192 + 64 + s * 16 + kh * 8);
        const half8 wq1 = *(const half8*)(wm1t + (32 + er) * 192 + 64 + s * 16 + kh * 8);
        P0 = mfma16(a[s], wp0, P0);
        P1 = mfma16(a[s], wp1, P1);
        Q0 = mfma16(a[s], wq0, Q0);
        Q1 = mfma16(a[s], wq1, Q1);
    }

    // store permuted: f=er (P0/Q0), f=32+er (P1/Q1)
    const int kh_t = (er >> 2) & 1;
    const int r_t = (er & 3) + 4 * ((er >> 3) & 3);
    #pragma unroll
    for (int r = 0; r < 16; ++r) {
        const int n = tile + (r & 3) + 8 * (r >> 2) + 4 * kh;
        if (n < Nn) {
            _Float16* row = pq + (size_t)n * 128;
            row[kh_t * 32 + r_t]           = (_Float16)P0[r];
            row[kh_t * 32 + 16 + r_t]      = (_Float16)P1[r];
            row[64 + kh_t * 32 + r_t]      = (_Float16)Q0[r];
            row[64 + kh_t * 32 + 16 + r_t] = (_Float16)Q1[r];
        }
    }
}

// ===========================================================================
// Edge kernel: 512-thr blocks, 29.7KB staged weights (Wm1 z-blocks hoisted
// into the PQ precompute). h1 acc initialized from PQp gathers (8 b128/lane,
// no DS, no MFMA). 26 MFMA + 26 ds_read/wave (was 42+42).
// ===========================================================================
__global__ __launch_bounds__(512) void edge_mfma_kernel(
    const float4* __restrict__ cent4,
    const int2* __restrict__ sd,
    const _Float16* __restrict__ wt, const _Float16* __restrict__ pq,
    const float* __restrict__ be1, const float* __restrict__ be2,
    const float* __restrict__ bm2,
    float* __restrict__ sums)
{
    __shared__ _Float16 swt[SWT_HALVES];   // 29696 B
    const int tid = threadIdx.x;
    const int wid = tid >> 6, lane = tid & 63;
    const int er = lane & 31;
    const int kh = lane >> 5;
    const int tile = (blockIdx.x * 8 + wid) * 32;   // 3125*8 = 25000 waves exact

    // ---- stage: We1 | We2 | Wm1c | Wm2 (1664 16B chunks) ----
    {
        const half8* __restrict__ g = (const half8*)wt;
        for (int i = tid; i < 1664; i += 512) {
            int gidx, dst;
            if (i < 128) {
                gidx = i;                       dst = SWE1 + i * 8;
            } else if (i < 640) {
                const int j = i - 128;
                gidx = 128 + j;                 dst = SWE2 + (j >> 3) * 72 + (j & 7) * 8;
            } else if (i < 1152) {
                const int j = i - 640;
                gidx = (WM1C >> 3) + j;         dst = SWM1C + (j >> 3) * 72 + (j & 7) * 8;
            } else {
                const int j = i - 1152;
                gidx = (WM2T >> 3) + j;         dst = SWM2 + (j >> 3) * 72 + (j & 7) * 8;
            }
            *(half8*)(swt + dst) = g[gidx];
        }
    }

    const int p = tile + er;
    const int2 e2i = sd[p];
    const int row = kh ? e2i.y : e2i.x;

    // ---- PQ gathers: P[src] segment + Q[dst] segment (64B each) ----
    const half8* __restrict__ prow = (const half8*)(pq + (size_t)e2i.x * 128 + kh * 32);
    const half8* __restrict__ qrow = (const half8*)(pq + (size_t)e2i.y * 128 + 64 + kh * 32);
    const half8 pf0 = prow[0], pf1 = prow[1], pf2 = prow[2], pf3 = prow[3];
    const half8 qf0 = qrow[0], qf1 = qrow[1], qf2 = qrow[2], qf3 = qrow[3];

    // ---- centroid delta (src vals in lanes 0-31, dst in 32-63) ----
    const float4 cv = cent4[row];
    const float d0 = __shfl(cv.x, er + 32, 64) - __shfl(cv.x, er, 64);
    const float d1 = __shfl(cv.y, er + 32, 64) - __shfl(cv.y, er, 64);
    const float d2 = __shfl(cv.z, er + 32, 64) - __shfl(cv.z, er, 64);

    __syncthreads();   // weights staged

    // ---- e1' = (delta @ We1)^T : K=16 (3 real) ----
    half8 bdel;
    #pragma unroll
    for (int j = 0; j < 8; ++j) bdel[j] = (_Float16)0.0f;
    if (kh == 0) { bdel[0] = (_Float16)d0; bdel[1] = (_Float16)d1; bdel[2] = (_Float16)d2; }

    unsigned pk0[8], pk1[8];
    {
        floatx16 A0, A1;
        #pragma unroll
        for (int r = 0; r < 16; ++r) { A0[r] = 0.0f; A1[r] = 0.0f; }
        const half8 w0 = *(const half8*)(swt + SWE1 + er * 16 + kh * 8);
        const half8 w1 = *(const half8*)(swt + SWE1 + (32 + er) * 16 + kh * 8);
        A0 = mfma16(w0, bdel, A0);
        A1 = mfma16(w1, bdel, A1);
        pack_acc(A0, be1, 0, kh, pk0);
        pack_acc(A1, be1, 32, kh, pk1);
    }

    // ---- e2' = (e1 @ We2)^T : K=64 ----
    unsigned qk0[8], qk1[8];
    {
        floatx16 B0, B1;
        #pragma unroll
        for (int r = 0; r < 16; ++r) { B0[r] = 0.0f; B1[r] = 0.0f; }
        #pragma unroll
        for (int s = 0; s < 4; ++s) {
            const half8 act = frag_from_pk((s < 2) ? pk0 : pk1, s & 1, kh);
            const half8 w0 = *(const half8*)(swt + SWE2 + er * 72 + s * 16 + kh * 8);
            const half8 w1 = *(const half8*)(swt + SWE2 + (32 + er) * 72 + s * 16 + kh * 8);
            B0 = mfma16(w0, act, B0);
            B1 = mfma16(w1, act, B1);
        }
        pack_acc(B0, be2, 0, kh, qk0);
        pack_acc(B1, be2, 32, kh, qk1);
    }

    // ---- h1' : init = P[src]+Q[dst] (bm1 folded in P), + e2 @ Wm1c ----
    unsigned rk0[8], rk1[8];
    {
        floatx16 C0, C1;
        #pragma unroll
        for (int r = 0; r < 8; ++r) {
            C0[r]     = (float)pf0[r] + (float)qf0[r];
            C0[8 + r] = (float)pf1[r] + (float)qf1[r];
            C1[r]     = (float)pf2[r] + (float)qf2[r];
            C1[8 + r] = (float)pf3[r] + (float)qf3[r];
        }
        #pragma unroll
        for (int s = 0; s < 4; ++s) {
            const half8 act = frag_from_pk((s < 2) ? qk0 : qk1, s & 1, kh);
            const half8 w0 = *(const half8*)(swt + SWM1C + er * 72 + s * 16 + kh * 8);
            const half8 w1 = *(const half8*)(swt + SWM1C + (32 + er) * 72 + s * 16 + kh * 8);
            C0 = mfma16(w0, act, C0);
            C1 = mfma16(w1, act, C1);
        }
        pack_acc_nb(C0, rk0);
        pack_acc_nb(C1, rk1);
    }

    // ---- m = h1 @ Wm2 + bm2 : NORMAL orientation (edges in C-rows) ----
    floatx16 M0, M1;
    {
        const float bias0 = bm2[er], bias1 = bm2[32 + er];
        #pragma unroll
        for (int r = 0; r < 16; ++r) { M0[r] = bias0; M1[r] = bias1; }
        #pragma unroll
        for (int s = 0; s < 4; ++s) {
            const half8 act = frag_from_pk((s < 2) ? rk0 : rk1, s & 1, kh);
            const half8 w0 = *(const half8*)(swt + SWM2 + er * 72 + s * 16 + kh * 8);
            const half8 w1 = *(const half8*)(swt + SWM2 + (32 + er) * 72 + s * 16 + kh * 8);
            M0 = mfma16(act, w0, M0);
            M1 = mfma16(act, w1, M1);
        }
    }

    // ---- segmented (by dst) reduction + coalesced atomics ----
    const int dprev = __shfl(e2i.y, (er + 31) & 31, 64);
    const bool boundary = (er == 0) || (e2i.y != dprev);
    unsigned int m32 = (unsigned int)__ballot(boundary);

    while (m32) {
        const int a = __builtin_ctz(m32);
        m32 &= m32 - 1;
        const int b = m32 ? __builtin_ctz(m32) : 32;
        float p0 = 0.0f, p1 = 0.0f;
        #pragma unroll
        for (int r = 0; r < 16; ++r) {
            const int rrow = (r & 3) + 8 * (r >> 2) + 4 * kh;
            if (rrow >= a && rrow < b) { p0 += M0[r]; p1 += M1[r]; }
        }
        p0 += __shfl_xor(p0, 32, 64);
        p1 += __shfl_xor(p1, 32, 64);
        const float val = kh ? p1 : p0;
        const int dseg = __shfl(e2i.y, a, 64);
        atomicAdd(&sums[(size_t)dseg * 64 + lane], val);
    }
}

// ===========================================================================
// Node kernel (MFMA): unchanged from R10.
// ===========================================================================
__global__ __launch_bounds__(256) void node_mfma_kernel(
    const float* __restrict__ z, const _Float16* __restrict__ wu1t,
    const float* __restrict__ bu1, const int* __restrict__ deg,
    float* __restrict__ out)
{
    __shared__ _Float16 swu[64 * 136];
    const int tid = threadIdx.x;
    const int wid = tid >> 6, lane = tid & 63;
    const int er = lane & 31, kh = lane >> 5;
    const int tile = (blockIdx.x * 4 + wid) * 32;
    const int node = tile + er;

    {
        const half8* __restrict__ g = (const half8*)wu1t;
        for (int i = tid; i < 1024; i += 256) {
            const half8 v = g[i];
            const int n = i >> 4, c = i & 15;
            *(half8*)(swu + n * 136 + c * 8) = v;
        }
    }

    const int nclamp = (node < Nn) ? node : (Nn - 1);
    const int dn = deg[nclamp];
    const float scale = kh ? (1.0f / fmaxf((float)dn, 1.0f)) : 1.0f;
    const float* __restrict__ rowp = kh ? (out + (size_t)nclamp * 64)
                                        : (z + (size_t)nclamp * 64);
    half8 vreg[8];
    #pragma unroll
    for (int c = 0; c < 8; ++c) {
        const float4 a4 = *(const float4*)(rowp + c * 8);
        const float4 b4 = *(const float4*)(rowp + c * 8 + 4);
        union { half8 h; unsigned u[4]; } hv;
        hv.u[0] = pkrtz(a4.x * scale, a4.y * scale);
        hv.u[1] = pkrtz(a4.z * scale, a4.w * scale);
        hv.u[2] = pkrtz(b4.x * scale, b4.y * scale);
        hv.u[3] = pkrtz(b4.z * scale, b4.w * scale);
        vreg[c] = hv.h;
    }

    __syncthreads();

    floatx16 M0, M1;
    const float bias0 = bu1[er], bias1 = bu1[32 + er];
    #pragma unroll
    for (int r = 0; r < 16; ++r) { M0[r] = bias0; M1[r] = bias1; }
    #pragma unroll
    for (int s = 0; s < 4; ++s) {
        union { half8 h; int i[4]; } u;
        u.h = vreg[2 * s + 1];
        #pragma unroll
        for (int q = 0; q < 4; ++q) u.i[q] = __shfl_xor(u.i[q], 32, 64);
        const half8 act = kh ? u.h : vreg[2 * s];
        const half8 w0 = *(const half8*)(swu + er * 136 + s * 16 + kh * 8);
        const half8 w1 = *(const half8*)(swu + (32 + er) * 136 + s * 16 + kh * 8);
        M0 = mfma16(act, w0, M0);
        M1 = mfma16(act, w1, M1);
    }
    #pragma unroll
    for (int s = 0; s < 4; ++s) {
        union { half8 h; int i[4]; } u;
        u.h = vreg[2 * s];
        #pragma unroll
        for (int q = 0; q < 4; ++q) u.i[q] = __shfl_xor(u.i[q], 32, 64);
        const half8 act = kh ? vreg[2 * s + 1] : u.h;
        const half8 w0 = *(const half8*)(swu + er * 136 + 64 + s * 16 + kh * 8);
        const half8 w1 = *(const half8*)(swu + (32 + er) * 136 + 64 + s * 16 + kh * 8);
        M0 = mfma16(act, w0, M0);
        M1 = mfma16(act, w1, M1);
    }

    #pragma unroll
    for (int r = 0; r < 16; ++r) {
        const int rrow = (r & 3) + 8 * (r >> 2) + 4 * kh;
        const int nrow = tile + rrow;
        if (nrow < Nn) {
            out[(size_t)nrow * 64 + er]      = fmaxf(M0[r], 0.0f);
            out[(size_t)nrow * 64 + 32 + er] = fmaxf(M1[r], 0.0f);
        }
    }
}

// ===========================================================================
// Fallback (atomic, fp32) — only if ws_size too small. Known-correct (R1).
// ===========================================================================
__global__ __launch_bounds__(256) void edge_kernel_atomic(
    const float* __restrict__ z, const float* __restrict__ cent,
    const int* __restrict__ ei,
    const float* __restrict__ We1, const float* __restrict__ be1,
    const float* __restrict__ We2, const float* __restrict__ be2,
    const float* __restrict__ Wm1, const float* __restrict__ bm1,
    const float* __restrict__ Wm2, const float* __restrict__ bm2,
    float* __restrict__ sums, float* __restrict__ cnt)
{
    __shared__ float buf[64][256];
    const int tid = threadIdx.x;
    const int e = blockIdx.x * 256 + tid;
    const int src = ei[e];
    const int dst = ei[Ee + e];
    const float d0 = cent[dst * 3 + 0] - cent[src * 3 + 0];
    const float d1 = cent[dst * 3 + 1] - cent[src * 3 + 1];
    const float d2 = cent[dst * 3 + 2] - cent[src * 3 + 2];
    for (int j = 0; j < 64; ++j) {
        float v = fmaf(d0, We1[j], fmaf(d1, We1[64 + j], fmaf(d2, We1[128 + j], be1[j])));
        buf[j][tid] = fmaxf(v, 0.0f);
    }
    float acc[64];
    #pragma unroll
    for (int j = 0; j < 64; ++j) acc[j] = be2[j];
    for (int k = 0; k < 64; ++k) {
        const float ek = buf[k][tid];
        const float* wrow = We2 + k * 64;
        #pragma unroll
        for (int j = 0; j < 64; ++j) acc[j] = fmaf(ek, wrow[j], acc[j]);
    }
    #pragma unroll
    for (int j = 0; j < 64; ++j) buf[j][tid] = fmaxf(acc[j], 0.0f);
    #pragma unroll
    for (int j = 0; j < 64; ++j) acc[j] = bm1[j];
    const float* zs = z + src * 64;
    for (int k = 0; k < 64; ++k) {
        const float hk = zs[k];
        const float* wrow = Wm1 + k * 64;
        #pragma unroll
        for (int j = 0; j < 64; ++j) acc[j] = fmaf(hk, wrow[j], acc[j]);
    }
    const float* zd = z + dst * 64;
    for (int k = 0; k < 64; ++k) {
        const float hk = zd[k];
        const float* wrow = Wm1 + (64 + k) * 64;
        #pragma unroll
        for (int j = 0; j < 64; ++j) acc[j] = fmaf(hk, wrow[j], acc[j]);
    }
    for (int k = 0; k < 64; ++k) {
        const float hk = buf[k][tid];
        const float* wrow = Wm1 + (128 + k) * 64;
        #pragma unroll
        for (int j = 0; j < 64; ++j) acc[j] = fmaf(hk, wrow[j], acc[j]);
    }
    #pragma unroll
    for (int j = 0; j < 64; ++j) buf[j][tid] = fmaxf(acc[j], 0.0f);
    #pragma unroll
    for (int j = 0; j < 64; ++j) acc[j] = bm2[j];
    for (int k = 0; k < 64; ++k) {
        const float hk = buf[k][tid];
        const float* wrow = Wm2 + k * 64;
        #pragma unroll
        for (int j = 0; j < 64; ++j) acc[j] = fmaf(hk, wrow[j], acc[j]);
    }
    float* srow = sums + dst * 64;
    #pragma unroll
    for (int j = 0; j < 64; ++j) atomicAdd(&srow[j], acc[j]);
    atomicAdd(&cnt[dst], 1.0f);
}

__global__ __launch_bounds__(256) void node_kernel_atomic(
    const float* __restrict__ z,
    const float* __restrict__ Wu1, const float* __restrict__ bu1,
    float* __restrict__ out, const float* __restrict__ cnt)
{
    const int node = (blockIdx.x * 256 + threadIdx.x) >> 6;
    const int j = threadIdx.x & 63;
    const int base = node * 64;
    const float inv = 1.0f / fmaxf(cnt[node], 1.0f);
    const float zj = z[base + j];
    const float mj = out[base + j] * inv;
    float a = bu1[j];
    for (int k = 0; k < 64; ++k)
        a = fmaf(__shfl(zj, k, 64), Wu1[k * 64 + j], a);
    for (int k = 0; k < 64; ++k)
        a = fmaf(__shfl(mj, k, 64), Wu1[(64 + k) * 64 + j], a);
    out[base + j] = fmaxf(a, 0.0f);
}

extern "C" void kernel_launch(void* const* d_in, const int* in_sizes, int n_in,
                              void* d_out, int out_size, void* d_ws, size_t ws_size,
                              hipStream_t stream) {
    const float* z    = (const float*)d_in[0];
    const float* cent = (const float*)d_in[1];
    const int*   ei   = (const int*)d_in[2];
    const float* We1  = (const float*)d_in[3];
    const float* be1  = (const float*)d_in[4];
    const float* We2  = (const float*)d_in[5];
    const float* be2  = (const float*)d_in[6];
    const float* Wm1  = (const float*)d_in[7];
    const float* bm1  = (const float*)d_in[8];
    const float* Wm2  = (const float*)d_in[9];
    const float* bm2  = (const float*)d_in[10];
    const float* Wu1  = (const float*)d_in[11];
    const float* bu1  = (const float*)d_in[12];
    float* out = (float*)d_out;

    if (ws_size >= TOTAL_WS) {
        int2* sd   = (int2*)((char*)d_ws + SD_OFF);
        int* deg   = (int*)((char*)d_ws + DEG_OFF);
        int* off   = (int*)((char*)d_ws + OFF_OFF);
        int* bsum  = (int*)((char*)d_ws + BSUM_OFF);
        int* rank  = (int*)((char*)d_ws + RANK_OFF);
        _Float16* wt  = (_Float16*)((char*)d_ws + WT_OFF);
        _Float16* wu  = (_Float16*)((char*)d_ws + WU_OFF);
        _Float16* z16 = (_Float16*)((char*)d_ws + Z16_OFF);
        _Float16* pq  = (_Float16*)((char*)d_ws + PQ_OFF);
        float4* cent4 = (float4*)((char*)d_ws + C4_OFF);

        hipMemsetAsync(deg, 0, Nn * sizeof(int), stream);
        prep_kernel<<<PREP_NB, 256, 0, stream>>>(z, cent, ei, We1, We2, Wm1, Wm2,
                                                 Wu1, z16, cent4, wt, wu, deg, rank);
        scan1_kernel<<<SCAN_NBLK, 1024, 0, stream>>>(deg, off, bsum);
        scan3_kernel<<<SCAN_NBLK, 1024, 0, stream>>>(off, bsum);
        fill_kernel<<<Ee / 256, 256, 0, stream>>>(ei, off, rank, sd, (float4*)out);
        pq_kernel<<<(Nn + 127) / 128, 256, 0, stream>>>(z16, wt, bm1, pq);
        edge_mfma_kernel<<<Ee / 256, 512, 0, stream>>>(cent4, sd, wt, pq,
            be1, be2, bm2, out);
        node_mfma_kernel<<<(Nn + 127) / 128, 256, 0, stream>>>(z, wu, bu1, deg, out);
    } else {
        float* cnt = (float*)d_ws;
        hipMemsetAsync(out, 0, (size_t)Nn * 64 * sizeof(float), stream);
        hipMemsetAsync(cnt, 0, (size_t)Nn * sizeof(float), stream);
        edge_kernel_atomic<<<Ee / 256, 256, 0, stream>>>(z, cent, ei,
            We1, be1, We2, be2, Wm1, bm1, Wm2, bm2, out, cnt);
        node_kernel_atomic<<<Nn / 4, 256, 0, stream>>>(z, Wu1, bu1, out, cnt);
    }
}

// Round 13
// 229.848 us; speedup vs baseline: 1.2049x; 1.0712x over previous
//
#include <hip/hip_runtime.h>

#define Nn 50000
#define Ee 800000

typedef _Float16 half8 __attribute__((ext_vector_type(8)));
typedef __fp16 fp16x2 __attribute__((ext_vector_type(2)));
typedef float floatx16 __attribute__((ext_vector_type(16)));

// ---- workspace layout (bytes) ----
#define SDD_OFF     0                                    // int4[Ee] (src,dst,delta f16x3)
#define DEG_OFF     (SDD_OFF + (size_t)Ee * 16)
#define OFF_OFF     (DEG_OFF + (size_t)Nn * 4)
#define BSUM_OFF    (OFF_OFF + (size_t)Nn * 4)
#define RANK_OFF    (BSUM_OFF + 256)                     // int[Ee]
#define WT_OFF      (RANK_OFF + (size_t)Ee * 4)
#define WT_HALVES   25600   // We1t 1024 | We2t 4096 | Wm1t 12288 | Wm2t 4096 | Wm1c 4096
#define WU_OFF      (WT_OFF + (size_t)WT_HALVES * 2)
#define WU_HALVES   8192
#define PQ_OFF      (WU_OFF + (size_t)WU_HALVES * 2)     // PQp f16 [Nn][128]
#define TOTAL_WS    (PQ_OFF + (size_t)Nn * 128 * 2)      // ~29 MB

// wt sub-offsets in GLOBAL packed table (halves)
#define WE1T 0
#define WE2T 1024
#define WM1T 5120
#define WM2T 17408
#define WM1C 21504   // compact e2-block of Wm1: [64][64]

// LDS padded layout (halves)
#define SWE1 0
#define SWE2 1024          // stride 72
#define SWM1C 5632         // stride 72
#define SWM2 10240         // stride 72
#define SWT_HALVES 14848   // 29696 B

// prep kernel grid partition
#define WT_NB   100
#define WU_NB   32
#define HI_NB   3125
#define PREP_NB (WT_NB + WU_NB + HI_NB)

// ===========================================================================
// Fused prep: weight tables, Wu1t, histogram+rank. (z16/cent4 passes deleted)
// ===========================================================================
__global__ __launch_bounds__(256) void prep_kernel(
    const int* __restrict__ ei,
    const float* __restrict__ We1, const float* __restrict__ We2,
    const float* __restrict__ Wm1, const float* __restrict__ Wm2,
    const float* __restrict__ Wu1,
    _Float16* __restrict__ wt, _Float16* __restrict__ wu,
    int* __restrict__ deg, int* __restrict__ rank)
{
    const int b = blockIdx.x, tid = threadIdx.x;
    if (b < WT_NB) {                                   // ---- weight tables
        const int i = b * 256 + tid;   // 100*256 = 25600 exact
        float v;
        if (i < 1024) {                      // We1t [64][16], K=3 zero-padded
            const int n = i >> 4, k = i & 15;
            v = (k < 3) ? We1[k * 64 + n] : 0.0f;
        } else if (i < 5120) {               // We2t [64][64]
            const int j = i - 1024, n = j >> 6, k = j & 63;
            v = We2[k * 64 + n];
        } else if (i < 17408) {              // Wm1t [64][192]
            const int j = i - 5120, n = j / 192, k = j - n * 192;
            v = Wm1[k * 64 + n];
        } else if (i < 21504) {              // Wm2t [64][64]
            const int j = i - 17408, n = j >> 6, k = j & 63;
            v = Wm2[k * 64 + n];
        } else {                             // Wm1c [64][64] (k 128..191)
            const int j = i - 21504, n = j >> 6, k = j & 63;
            v = Wm1[(128 + k) * 64 + n];
        }
        wt[i] = (_Float16)v;
    } else if (b < WT_NB + WU_NB) {                    // ---- Wu1t [64][128]
        const int i = (b - WT_NB) * 256 + tid;
        const int n = i >> 7, k = i & 127;
        wu[i] = (_Float16)Wu1[k * 64 + n];
    } else {                                           // ---- histogram + rank
        const int e = (b - WT_NB - WU_NB) * 256 + tid;
        rank[e] = atomicAdd(&deg[ei[Ee + e]], 1);
    }
}

// ===========================================================================
// Exclusive scan of deg[Nn]: scan1 -> block-local off + bsum; scan2 -> 13-way
// exclusive prefix in-place; fill adds bsum[d>>12].
// ===========================================================================
#define SCAN_TILE 4096
#define SCAN_NBLK 13

__global__ __launch_bounds__(1024) void scan1_kernel(const int* __restrict__ deg,
                                                     int* __restrict__ off,
                                                     int* __restrict__ bsum) {
    __shared__ int wsum[16];
    const int tid = threadIdx.x;
    const int lane = tid & 63, wid = tid >> 6;
    const int base = blockIdx.x * SCAN_TILE + tid * 4;

    int v0 = (base + 0 < Nn) ? deg[base + 0] : 0;
    int v1 = (base + 1 < Nn) ? deg[base + 1] : 0;
    int v2 = (base + 2 < Nn) ? deg[base + 2] : 0;
    int v3 = (base + 3 < Nn) ? deg[base + 3] : 0;
    const int tsum = v0 + v1 + v2 + v3;

    int x = tsum;
    for (int s = 1; s < 64; s <<= 1) {
        int y = __shfl_up(x, s, 64);
        if (lane >= s) x += y;
    }
    if (lane == 63) wsum[wid] = x;
    __syncthreads();
    if (wid == 0) {
        int w = (lane < 16) ? wsum[lane] : 0;
        for (int s = 1; s < 16; s <<= 1) {
            int y = __shfl_up(w, s, 64);
            if (lane >= s) w += y;
        }
        if (lane < 16) wsum[lane] = w;
    }
    __syncthreads();
    const int wpre = wid ? wsum[wid - 1] : 0;
    const int tpre = wpre + (x - tsum);
    if (base + 0 < Nn) off[base + 0] = tpre;
    if (base + 1 < Nn) off[base + 1] = tpre + v0;
    if (base + 2 < Nn) off[base + 2] = tpre + v0 + v1;
    if (base + 3 < Nn) off[base + 3] = tpre + v0 + v1 + v2;
    if (tid == 1023) bsum[blockIdx.x] = wsum[15];
}

__global__ __launch_bounds__(64) void scan2_kernel(int* __restrict__ bsum) {
    const int lane = threadIdx.x;
    int v = (lane < SCAN_NBLK) ? bsum[lane] : 0;
    int w = v;
    for (int s = 1; s < 64; s <<= 1) {
        int y = __shfl_up(w, s, 64);
        if (lane >= s) w += y;
    }
    if (lane < SCAN_NBLK) bsum[lane] = w - v;      // exclusive
}

// Atomic-free scatter with packed delta. Also zeroes sums (d_out).
__global__ __launch_bounds__(256) void fill_kernel(const int* __restrict__ ei,
                                                   const int* __restrict__ off,
                                                   const int* __restrict__ bsum,
                                                   const int* __restrict__ rank,
                                                   const float* __restrict__ cent,
                                                   int4* __restrict__ sdd,
                                                   float4* __restrict__ sums4) {
    const int e = blockIdx.x * 256 + threadIdx.x;
    const int s = ei[e];
    const int d = ei[Ee + e];
    sums4[e] = make_float4(0.f, 0.f, 0.f, 0.f);   // Ee float4 = Nn*64 floats exact

    const float d0 = cent[d * 3 + 0] - cent[s * 3 + 0];
    const float d1 = cent[d * 3 + 1] - cent[s * 3 + 1];
    const float d2 = cent[d * 3 + 2] - cent[s * 3 + 2];
    union { fp16x2 h; int i; } p01, p2;
    p01.h = __builtin_amdgcn_cvt_pkrtz(d0, d1);
    p2.h  = __builtin_amdgcn_cvt_pkrtz(d2, 0.0f);

    const int pos = off[d] + bsum[d >> 12] + rank[e];
    sdd[pos] = make_int4(s, d, p01.i, p2.i);
}

// ===========================================================================
// MFMA helpers
//   A/B frag (32x32x16, isomorphic): lane&31 = non-K dim, regs = 8 contig k
//   C/D: row=(r&3)+8*(r>>2)+4*(lane>>5), col=lane&31
// ===========================================================================
__device__ __forceinline__ floatx16 mfma16(half8 a, half8 b, floatx16 c) {
    return __builtin_amdgcn_mfma_f32_32x32x16_f16(a, b, c, 0, 0, 0);
}

__device__ __forceinline__ unsigned pkrtz(float a, float b) {
    union { fp16x2 h; unsigned u; } c;
    c.h = __builtin_amdgcn_cvt_pkrtz(a, b);
    return c.u;
}

__device__ __forceinline__ void pack_acc(const floatx16& acc, const float* bias,
                                         int boff, int kh, unsigned* pk) {
    #pragma unroll
    for (int q = 0; q < 8; ++q) {
        const int r0 = 2 * q, r1 = 2 * q + 1;
        const int f0 = (r0 & 3) + 8 * (r0 >> 2);
        const int f1 = (r1 & 3) + 8 * (r1 >> 2);
        const float ba = kh ? bias[boff + f0 + 4] : bias[boff + f0];
        const float bb = kh ? bias[boff + f1 + 4] : bias[boff + f1];
        pk[q] = pkrtz(fmaxf(acc[r0] + ba, 0.0f), fmaxf(acc[r1] + bb, 0.0f));
    }
}

__device__ __forceinline__ void pack_acc_nb(const floatx16& acc, unsigned* pk) {
    #pragma unroll
    for (int q = 0; q < 8; ++q)
        pk[q] = pkrtz(fmaxf(acc[2 * q], 0.0f), fmaxf(acc[2 * q + 1], 0.0f));
}

__device__ __forceinline__ half8 frag_from_pk(const unsigned* pk, int s1, int kh) {
    const unsigned lo0 = pk[4 * s1], lo1 = pk[4 * s1 + 1];
    const unsigned hi0 = pk[4 * s1 + 2], hi1 = pk[4 * s1 + 3];
    const unsigned X0 = kh ? lo0 : hi0;
    const unsigned X1 = kh ? lo1 : hi1;
    const unsigned r0 = (unsigned)__shfl_xor((int)X0, 32, 64);
    const unsigned r1 = (unsigned)__shfl_xor((int)X1, 32, 64);
    union { half8 h; unsigned u[4]; } f;
    f.u[0] = kh ? r0 : lo0;
    f.u[1] = kh ? r1 : lo1;
    f.u[2] = kh ? hi0 : r0;
    f.u[3] = kh ? hi1 : r1;
    return f.h;
}

// ===========================================================================
// PQ kernel: per-node P = z@Wm1[0:64] + bm1, Q = z@Wm1[64:128], f16, stored
// C-fragment-permuted (see R12). Reads fp32 z directly (z16 pass deleted).
// ===========================================================================
__global__ __launch_bounds__(256) void pq_kernel(
    const float* __restrict__ z, const _Float16* __restrict__ wt,
    const float* __restrict__ bm1, _Float16* __restrict__ pq)
{
    const int tid = threadIdx.x;
    const int wid = tid >> 6, lane = tid & 63;
    const int er = lane & 31, kh = lane >> 5;
    const int tile = (blockIdx.x * 4 + wid) * 32;
    const int nclamp = (tile + er < Nn) ? (tile + er) : (Nn - 1);

    const float* __restrict__ zr = z + (size_t)nclamp * 64;
    half8 a[4];
    #pragma unroll
    for (int s = 0; s < 4; ++s) {
        const int base = s * 16 + kh * 8;
        const float4 u = *(const float4*)(zr + base);
        const float4 v = *(const float4*)(zr + base + 4);
        union { half8 h; unsigned w[4]; } hv;
        hv.w[0] = pkrtz(u.x, u.y);
        hv.w[1] = pkrtz(u.z, u.w);
        hv.w[2] = pkrtz(v.x, v.y);
        hv.w[3] = pkrtz(v.z, v.w);
        a[s] = hv.h;
    }

    const _Float16* __restrict__ wm1t = wt + WM1T;
    floatx16 P0, P1, Q0, Q1;
    const float b0 = bm1[er], b1 = bm1[32 + er];
    #pragma unroll
    for (int r = 0; r < 16; ++r) { P0[r] = b0; P1[r] = b1; Q0[r] = 0.f; Q1[r] = 0.f; }

    #pragma unroll
    for (int s = 0; s < 4; ++s) {
        const half8 wp0 = *(const half8*)(wm1t + er * 192 + s * 16 + kh * 8);
        const half8 wp1 = *(const half8*)(wm1t + (32 + er) * 192 + s * 16 + kh * 8);
        const half8 wq0 = *(const half8*)(wm1t + er * 192 + 64 + s * 16 + kh * 8);
        const half8 wq1 = *(const half8*)(wm1t + (32 + er) * 192 + 64 + s * 16 + kh * 8);
        P0 = mfma16(a[s], wp0, P0);
        P1 = mfma16(a[s], wp1, P1);
        Q0 = mfma16(a[s], wq0, Q0);
        Q1 = mfma16(a[s], wq1, Q1);
    }

    const int kh_t = (er >> 2) & 1;
    const int r_t = (er & 3) + 4 * ((er >> 3) & 3);
    #pragma unroll
    for (int r = 0; r < 16; ++r) {
        const int n = tile + (r & 3) + 8 * (r >> 2) + 4 * kh;
        if (n < Nn) {
            _Float16* row = pq + (size_t)n * 128;
            row[kh_t * 32 + r_t]           = (_Float16)P0[r];
            row[kh_t * 32 + 16 + r_t]      = (_Float16)P1[r];
            row[64 + kh_t * 32 + r_t]      = (_Float16)Q0[r];
            row[64 + kh_t * 32 + 16 + r_t] = (_Float16)Q1[r];
        }
    }
}

// ===========================================================================
// Edge kernel: delta arrives pre-packed f16 in sdd (no cent gather, no delta
// bpermutes). Otherwise R12 structure: 29.7KB staged weights, PQ-initialized
// h1, 26 MFMA/wave, segmented-atomic epilogue.
// ===========================================================================
__global__ __launch_bounds__(512) void edge_mfma_kernel(
    const int4* __restrict__ sdd,
    const _Float16* __restrict__ wt, const _Float16* __restrict__ pq,
    const float* __restrict__ be1, const float* __restrict__ be2,
    const float* __restrict__ bm2,
    float* __restrict__ sums)
{
    __shared__ _Float16 swt[SWT_HALVES];   // 29696 B
    const int tid = threadIdx.x;
    const int wid = tid >> 6, lane = tid & 63;
    const int er = lane & 31;
    const int kh = lane >> 5;
    const int tile = (blockIdx.x * 8 + wid) * 32;   // 3125*8 = 25000 waves exact

    // ---- stage: We1 | We2 | Wm1c | Wm2 (1664 16B chunks) ----
    {
        const half8* __restrict__ g = (const half8*)wt;
        for (int i = tid; i < 1664; i += 512) {
            int gidx, dst;
            if (i < 128) {
                gidx = i;                       dst = SWE1 + i * 8;
            } else if (i < 640) {
                const int j = i - 128;
                gidx = 128 + j;                 dst = SWE2 + (j >> 3) * 72 + (j & 7) * 8;
            } else if (i < 1152) {
                const int j = i - 640;
                gidx = (WM1C >> 3) + j;         dst = SWM1C + (j >> 3) * 72 + (j & 7) * 8;
            } else {
                const int j = i - 1152;
                gidx = (WM2T >> 3) + j;         dst = SWM2 + (j >> 3) * 72 + (j & 7) * 8;
            }
            *(half8*)(swt + dst) = g[gidx];
        }
    }

    const int p = tile + er;
    const int4 ed = sdd[p];          // (src, dst, delta01, delta2_) coalesced 16B

    // ---- PQ gathers: P[src] segment + Q[dst] segment (64B each) ----
    const half8* __restrict__ prow = (const half8*)(pq + (size_t)ed.x * 128 + kh * 32);
    const half8* __restrict__ qrow = (const half8*)(pq + (size_t)ed.y * 128 + 64 + kh * 32);
    const half8 pf0 = prow[0], pf1 = prow[1], pf2 = prow[2], pf3 = prow[3];
    const half8 qf0 = qrow[0], qf1 = qrow[1], qf2 = qrow[2], qf3 = qrow[3];

    __syncthreads();   // weights staged

    // ---- e1' = (delta @ We1)^T : K=16 (3 real) ----
    half8 bdel;
    #pragma unroll
    for (int j = 0; j < 8; ++j) bdel[j] = (_Float16)0.0f;
    if (kh == 0) {
        union { int i; _Float16 h[2]; } u01, u2;
        u01.i = ed.z; u2.i = ed.w;
        bdel[0] = u01.h[0]; bdel[1] = u01.h[1]; bdel[2] = u2.h[0];
    }

    unsigned pk0[8], pk1[8];
    {
        floatx16 A0, A1;
        #pragma unroll
        for (int r = 0; r < 16; ++r) { A0[r] = 0.0f; A1[r] = 0.0f; }
        const half8 w0 = *(const half8*)(swt + SWE1 + er * 16 + kh * 8);
        const half8 w1 = *(const half8*)(swt + SWE1 + (32 + er) * 16 + kh * 8);
        A0 = mfma16(w0, bdel, A0);
        A1 = mfma16(w1, bdel, A1);
        pack_acc(A0, be1, 0, kh, pk0);
        pack_acc(A1, be1, 32, kh, pk1);
    }

    // ---- e2' = (e1 @ We2)^T : K=64 ----
    unsigned qk0[8], qk1[8];
    {
        floatx16 B0, B1;
        #pragma unroll
        for (int r = 0; r < 16; ++r) { B0[r] = 0.0f; B1[r] = 0.0f; }
        #pragma unroll
        for (int s = 0; s < 4; ++s) {
            const half8 act = frag_from_pk((s < 2) ? pk0 : pk1, s & 1, kh);
            const half8 w0 = *(const half8*)(swt + SWE2 + er * 72 + s * 16 + kh * 8);
            const half8 w1 = *(const half8*)(swt + SWE2 + (32 + er) * 72 + s * 16 + kh * 8);
            B0 = mfma16(w0, act, B0);
            B1 = mfma16(w1, act, B1);
        }
        pack_acc(B0, be2, 0, kh, qk0);
        pack_acc(B1, be2, 32, kh, qk1);
    }

    // ---- h1' : init = P[src]+Q[dst] (bm1 folded in P), + e2 @ Wm1c ----
    unsigned rk0[8], rk1[8];
    {
        floatx16 C0, C1;
        #pragma unroll
        for (int r = 0; r < 8; ++r) {
            C0[r]     = (float)pf0[r] + (float)qf0[r];
            C0[8 + r] = (float)pf1[r] + (float)qf1[r];
            C1[r]     = (float)pf2[r] + (float)qf2[r];
            C1[8 + r] = (float)pf3[r] + (float)qf3[r];
        }
        #pragma unroll
        for (int s = 0; s < 4; ++s) {
            const half8 act = frag_from_pk((s < 2) ? qk0 : qk1, s & 1, kh);
            const half8 w0 = *(const half8*)(swt + SWM1C + er * 72 + s * 16 + kh * 8);
            const half8 w1 = *(const half8*)(swt + SWM1C + (32 + er) * 72 + s * 16 + kh * 8);
            C0 = mfma16(w0, act, C0);
            C1 = mfma16(w1, act, C1);
        }
        pack_acc_nb(C0, rk0);
        pack_acc_nb(C1, rk1);
    }

    // ---- m = h1 @ Wm2 + bm2 : NORMAL orientation (edges in C-rows) ----
    floatx16 M0, M1;
    {
        const float bias0 = bm2[er], bias1 = bm2[32 + er];
        #pragma unroll
        for (int r = 0; r < 16; ++r) { M0[r] = bias0; M1[r] = bias1; }
        #pragma unroll
        for (int s = 0; s < 4; ++s) {
            const half8 act = frag_from_pk((s < 2) ? rk0 : rk1, s & 1, kh);
            const half8 w0 = *(const half8*)(swt + SWM2 + er * 72 + s * 16 + kh * 8);
            const half8 w1 = *(const half8*)(swt + SWM2 + (32 + er) * 72 + s * 16 + kh * 8);
            M0 = mfma16(act, w0, M0);
            M1 = mfma16(act, w1, M1);
        }
    }

    // ---- segmented (by dst) reduction + coalesced atomics ----
    const int dprev = __shfl(ed.y, (er + 31) & 31, 64);
    const bool boundary = (er == 0) || (ed.y != dprev);
    unsigned int m32 = (unsigned int)__ballot(boundary);

    while (m32) {
        const int a = __builtin_ctz(m32);
        m32 &= m32 - 1;
        const int b = m32 ? __builtin_ctz(m32) : 32;
        float p0 = 0.0f, p1 = 0.0f;
        #pragma unroll
        for (int r = 0; r < 16; ++r) {
            const int rrow = (r & 3) + 8 * (r >> 2) + 4 * kh;
            if (rrow >= a && rrow < b) { p0 += M0[r]; p1 += M1[r]; }
        }
        p0 += __shfl_xor(p0, 32, 64);
        p1 += __shfl_xor(p1, 32, 64);
        const float val = kh ? p1 : p0;
        const int dseg = __shfl(ed.y, a, 64);
        atomicAdd(&sums[(size_t)dseg * 64 + lane], val);
    }
}

// ===========================================================================
// Node kernel (MFMA): unchanged from R10/R12.
// ===========================================================================
__global__ __launch_bounds__(256) void node_mfma_kernel(
    const float* __restrict__ z, const _Float16* __restrict__ wu1t,
    const float* __restrict__ bu1, const int* __restrict__ deg,
    float* __restrict__ out)
{
    __shared__ _Float16 swu[64 * 136];
    const int tid = threadIdx.x;
    const int wid = tid >> 6, lane = tid & 63;
    const int er = lane & 31, kh = lane >> 5;
    const int tile = (blockIdx.x * 4 + wid) * 32;
    const int node = tile + er;

    {
        const half8* __restrict__ g = (const half8*)wu1t;
        for (int i = tid; i < 1024; i += 256) {
            const half8 v = g[i];
            const int n = i >> 4, c = i & 15;
            *(half8*)(swu + n * 136 + c * 8) = v;
        }
    }

    const int nclamp = (node < Nn) ? node : (Nn - 1);
    const int dn = deg[nclamp];
    const float scale = kh ? (1.0f / fmaxf((float)dn, 1.0f)) : 1.0f;
    const float* __restrict__ rowp = kh ? (out + (size_t)nclamp * 64)
                                        : (z + (size_t)nclamp * 64);
    half8 vreg[8];
    #pragma unroll
    for (int c = 0; c < 8; ++c) {
        const float4 a4 = *(const float4*)(rowp + c * 8);
        const float4 b4 = *(const float4*)(rowp + c * 8 + 4);
        union { half8 h; unsigned u[4]; } hv;
        hv.u[0] = pkrtz(a4.x * scale, a4.y * scale);
        hv.u[1] = pkrtz(a4.z * scale, a4.w * scale);
        hv.u[2] = pkrtz(b4.x * scale, b4.y * scale);
        hv.u[3] = pkrtz(b4.z * scale, b4.w * scale);
        vreg[c] = hv.h;
    }

    __syncthreads();

    floatx16 M0, M1;
    const float bias0 = bu1[er], bias1 = bu1[32 + er];
    #pragma unroll
    for (int r = 0; r < 16; ++r) { M0[r] = bias0; M1[r] = bias1; }
    #pragma unroll
    for (int s = 0; s < 4; ++s) {
        union { half8 h; int i[4]; } u;
        u.h = vreg[2 * s + 1];
        #pragma unroll
        for (int q = 0; q < 4; ++q) u.i[q] = __shfl_xor(u.i[q], 32, 64);
        const half8 act = kh ? u.h : vreg[2 * s];
        const half8 w0 = *(const half8*)(swu + er * 136 + s * 16 + kh * 8);
        const half8 w1 = *(const half8*)(swu + (32 + er) * 136 + s * 16 + kh * 8);
        M0 = mfma16(act, w0, M0);
        M1 = mfma16(act, w1, M1);
    }
    #pragma unroll
    for (int s = 0; s < 4; ++s) {
        union { half8 h; int i[4]; } u;
        u.h = vreg[2 * s];
        #pragma unroll
        for (int q = 0; q < 4; ++q) u.i[q] = __shfl_xor(u.i[q], 32, 64);
        const half8 act = kh ? vreg[2 * s + 1] : u.h;
        const half8 w0 = *(const half8*)(swu + er * 136 + 64 + s * 16 + kh * 8);
        const half8 w1 = *(const half8*)(swu + (32 + er) * 136 + 64 + s * 16 + kh * 8);
        M0 = mfma16(act, w0, M0);
        M1 = mfma16(act, w1, M1);
    }

    #pragma unroll
    for (int r = 0; r < 16; ++r) {
        const int rrow = (r & 3) + 8 * (r >> 2) + 4 * kh;
        const int nrow = tile + rrow;
        if (nrow < Nn) {
            out[(size_t)nrow * 64 + er]      = fmaxf(M0[r], 0.0f);
            out[(size_t)nrow * 64 + 32 + er] = fmaxf(M1[r], 0.0f);
        }
    }
}

// ===========================================================================
// Fallback (atomic, fp32) — only if ws_size too small. Known-correct (R1).
// ===========================================================================
__global__ __launch_bounds__(256) void edge_kernel_atomic(
    const float* __restrict__ z, const float* __restrict__ cent,
    const int* __restrict__ ei,
    const float* __restrict__ We1, const float* __restrict__ be1,
    const float* __restrict__ We2, const float* __restrict__ be2,
    const float* __restrict__ Wm1, const float* __restrict__ bm1,
    const float* __restrict__ Wm2, const float* __restrict__ bm2,
    float* __restrict__ sums, float* __restrict__ cnt)
{
    __shared__ float buf[64][256];
    const int tid = threadIdx.x;
    const int e = blockIdx.x * 256 + tid;
    const int src = ei[e];
    const int dst = ei[Ee + e];
    const float d0 = cent[dst * 3 + 0] - cent[src * 3 + 0];
    const float d1 = cent[dst * 3 + 1] - cent[src * 3 + 1];
    const float d2 = cent[dst * 3 + 2] - cent[src * 3 + 2];
    for (int j = 0; j < 64; ++j) {
        float v = fmaf(d0, We1[j], fmaf(d1, We1[64 + j], fmaf(d2, We1[128 + j], be1[j])));
        buf[j][tid] = fmaxf(v, 0.0f);
    }
    float acc[64];
    #pragma unroll
    for (int j = 0; j < 64; ++j) acc[j] = be2[j];
    for (int k = 0; k < 64; ++k) {
        const float ek = buf[k][tid];
        const float* wrow = We2 + k * 64;
        #pragma unroll
        for (int j = 0; j < 64; ++j) acc[j] = fmaf(ek, wrow[j], acc[j]);
    }
    #pragma unroll
    for (int j = 0; j < 64; ++j) buf[j][tid] = fmaxf(acc[j], 0.0f);
    #pragma unroll
    for (int j = 0; j < 64; ++j) acc[j] = bm1[j];
    const float* zs = z + src * 64;
    for (int k = 0; k < 64; ++k) {
        const float hk = zs[k];
        const float* wrow = Wm1 + k * 64;
        #pragma unroll
        for (int j = 0; j < 64; ++j) acc[j] = fmaf(hk, wrow[j], acc[j]);
    }
    const float* zd = z + dst * 64;
    for (int k = 0; k < 64; ++k) {
        const float hk = zd[k];
        const float* wrow = Wm1 + (64 + k) * 64;
        #pragma unroll
        for (int j = 0; j < 64; ++j) acc[j] = fmaf(hk, wrow[j], acc[j]);
    }
    for (int k = 0; k < 64; ++k) {
        const float hk = buf[k][tid];
        const float* wrow = Wm1 + (128 + k) * 64;
        #pragma unroll
        for (int j = 0; j < 64; ++j) acc[j] = fmaf(hk, wrow[j], acc[j]);
    }
    #pragma unroll
    for (int j = 0; j < 64; ++j) buf[j][tid] = fmaxf(acc[j], 0.0f);
    #pragma unroll
    for (int j = 0; j < 64; ++j) acc[j] = bm2[j];
    for (int k = 0; k < 64; ++k) {
        const float hk = buf[k][tid];
        const float* wrow = Wm2 + k * 64;
        #pragma unroll
        for (int j = 0; j < 64; ++j) acc[j] = fmaf(hk, wrow[j], acc[j]);
    }
    float* srow = sums + dst * 64;
    #pragma unroll
    for (int j = 0; j < 64; ++j) atomicAdd(&srow[j], acc[j]);
    atomicAdd(&cnt[dst], 1.0f);
}

__global__ __launch_bounds__(256) void node_kernel_atomic(
    const float* __restrict__ z,
    const float* __restrict__ Wu1, const float* __restrict__ bu1,
    float* __restrict__ out, const float* __restrict__ cnt)
{
    const int node = (blockIdx.x * 256 + threadIdx.x) >> 6;
    const int j = threadIdx.x & 63;
    const int base = node * 64;
    const float inv = 1.0f / fmaxf(cnt[node], 1.0f);
    const float zj = z[base + j];
    const float mj = out[base + j] * inv;
    float a = bu1[j];
    for (int k = 0; k < 64; ++k)
        a = fmaf(__shfl(zj, k, 64), Wu1[k * 64 + j], a);
    for (int k = 0; k < 64; ++k)
        a = fmaf(__shfl(mj, k, 64), Wu1[(64 + k) * 64 + j], a);
    out[base + j] = fmaxf(a, 0.0f);
}

extern "C" void kernel_launch(void* const* d_in, const int* in_sizes, int n_in,
                              void* d_out, int out_size, void* d_ws, size_t ws_size,
                              hipStream_t stream) {
    const float* z    = (const float*)d_in[0];
    const float* cent = (const float*)d_in[1];
    const int*   ei   = (const int*)d_in[2];
    const float* We1  = (const float*)d_in[3];
    const float* be1  = (const float*)d_in[4];
    const float* We2  = (const float*)d_in[5];
    const float* be2  = (const float*)d_in[6];
    const float* Wm1  = (const float*)d_in[7];
    const float* bm1  = (const float*)d_in[8];
    const float* Wm2  = (const float*)d_in[9];
    const float* bm2  = (const float*)d_in[10];
    const float* Wu1  = (const float*)d_in[11];
    const float* bu1  = (const float*)d_in[12];
    float* out = (float*)d_out;

    if (ws_size >= TOTAL_WS) {
        int4* sdd  = (int4*)((char*)d_ws + SDD_OFF);
        int* deg   = (int*)((char*)d_ws + DEG_OFF);
        int* off   = (int*)((char*)d_ws + OFF_OFF);
        int* bsum  = (int*)((char*)d_ws + BSUM_OFF);
        int* rank  = (int*)((char*)d_ws + RANK_OFF);
        _Float16* wt  = (_Float16*)((char*)d_ws + WT_OFF);
        _Float16* wu  = (_Float16*)((char*)d_ws + WU_OFF);
        _Float16* pq  = (_Float16*)((char*)d_ws + PQ_OFF);

        hipMemsetAsync(deg, 0, Nn * sizeof(int), stream);
        prep_kernel<<<PREP_NB, 256, 0, stream>>>(ei, We1, We2, Wm1, Wm2, Wu1,
                                                 wt, wu, deg, rank);
        scan1_kernel<<<SCAN_NBLK, 1024, 0, stream>>>(deg, off, bsum);
        scan2_kernel<<<1, 64, 0, stream>>>(bsum);
        fill_kernel<<<Ee / 256, 256, 0, stream>>>(ei, off, bsum, rank, cent,
                                                  sdd, (float4*)out);
        pq_kernel<<<(Nn + 127) / 128, 256, 0, stream>>>(z, wt, bm1, pq);
        edge_mfma_kernel<<<Ee / 256, 512, 0, stream>>>(sdd, wt, pq,
            be1, be2, bm2, out);
        node_mfma_kernel<<<(Nn + 127) / 128, 256, 0, stream>>>(z, wu, bu1, deg, out);
    } else {
        float* cnt = (float*)d_ws;
        hipMemsetAsync(out, 0, (size_t)Nn * 64 * sizeof(float), stream);
        hipMemsetAsync(cnt, 0, (size_t)Nn * sizeof(float), stream);
        edge_kernel_atomic<<<Ee / 256, 256, 0, stream>>>(z, cent, ei,
            We1, be1, We2, be2, Wm1, bm1, Wm2, bm2, out, cnt);
        node_kernel_atomic<<<Nn / 4, 256, 0, stream>>>(z, Wu1, bu1, out, cnt);
    }
}

// Round 14
// 213.042 us; speedup vs baseline: 1.2999x; 1.0789x over previous
//
#include <hip/hip_runtime.h>

#define Nn 50000
#define Ee 800000

typedef _Float16 half8 __attribute__((ext_vector_type(8)));
typedef __fp16 fp16x2 __attribute__((ext_vector_type(2)));
typedef float floatx16 __attribute__((ext_vector_type(16)));

// ---- workspace layout (bytes) ----
#define SDD_OFF     0                                    // int4[Ee] (src,dst,delta f16x3)
#define DEG_OFF     (SDD_OFF + (size_t)Ee * 16)
#define OFF_OFF     (DEG_OFF + (size_t)Nn * 4)
#define BSUM_OFF    (OFF_OFF + (size_t)Nn * 4)
#define RANK_OFF    (BSUM_OFF + 256)                     // int[Ee]
#define WT_OFF      (RANK_OFF + (size_t)Ee * 4)
#define WT_HALVES   25728   // ... | Wm1c 4096 | packed-bias 128
#define WU_OFF      (WT_OFF + (size_t)WT_HALVES * 2)
#define WU_HALVES   8192
#define PQ_OFF      (WU_OFF + (size_t)WU_HALVES * 2)     // PQp f16 [Nn][128]
#define TOTAL_WS    (PQ_OFF + (size_t)Nn * 128 * 2)      // ~29 MB

// wt sub-offsets in GLOBAL packed table (halves)
#define WE1T 0
#define WE2T 1024
#define WM1T 5120
#define WM2T 17408
#define WM1C 21504   // compact e2-block of Wm1: [64][64]
#define PBIAS 25600  // packed f16 bias pairs: [layer][boff][kh][q] dwords

// LDS padded layout (halves)
#define SWE1 0
#define SWE2 1024          // stride 72
#define SWM1C 5632         // stride 72
#define SWM2 10240         // stride 72
#define SPB  14848         // packed bias, 128 halves
#define SWT_HALVES 14976   // 29952 B

// prep kernel grid partition
#define WT_NB   101
#define WU_NB   32
#define HI_NB   3125
#define PREP_NB (WT_NB + WU_NB + HI_NB)

#define SCAN_TILE 4096
#define SCAN_NBLK 13
#define FILL_NB   3125
#define PQ_NB     391      // ceil(50000/128)
#define FILLPQ_NB (FILL_NB + PQ_NB)

// ===========================================================================
// Fused prep: weight tables (+packed bias), Wu1t, histogram+rank.
// ===========================================================================
__global__ __launch_bounds__(256) void prep_kernel(
    const int* __restrict__ ei,
    const float* __restrict__ We1, const float* __restrict__ We2,
    const float* __restrict__ Wm1, const float* __restrict__ Wm2,
    const float* __restrict__ Wu1,
    const float* __restrict__ be1, const float* __restrict__ be2,
    _Float16* __restrict__ wt, _Float16* __restrict__ wu,
    int* __restrict__ deg, int* __restrict__ rank)
{
    const int b = blockIdx.x, tid = threadIdx.x;
    if (b < WT_NB) {                                   // ---- weight tables
        const int i = b * 256 + tid;
        if (i < 25728) {
            float v;
            if (i < 1024) {                      // We1t [64][16], K=3 zero-padded
                const int n = i >> 4, k = i & 15;
                v = (k < 3) ? We1[k * 64 + n] : 0.0f;
            } else if (i < 5120) {               // We2t [64][64]
                const int j = i - 1024, n = j >> 6, k = j & 63;
                v = We2[k * 64 + n];
            } else if (i < 17408) {              // Wm1t [64][192]
                const int j = i - 5120, n = j / 192, k = j - n * 192;
                v = Wm1[k * 64 + n];
            } else if (i < 21504) {              // Wm2t [64][64]
                const int j = i - 17408, n = j >> 6, k = j & 63;
                v = Wm2[k * 64 + n];
            } else if (i < 25600) {              // Wm1c [64][64] (k 128..191)
                const int j = i - 21504, n = j >> 6, k = j & 63;
                v = Wm1[(128 + k) * 64 + n];
            } else {                             // packed bias pairs
                const int t = i - 25600;         // half idx 0..127
                const int j = t >> 1, which = t & 1;
                const int layer = j >> 5, rem = j & 31;
                const int boff = (rem >> 4) & 1, kh = (rem >> 3) & 1, q = rem & 7;
                const int r = 2 * q + which;
                const int f = (r & 3) + 8 * (r >> 2) + 4 * kh + 32 * boff;
                v = layer ? be2[f] : be1[f];
            }
            wt[i] = (_Float16)v;
        }
    } else if (b < WT_NB + WU_NB) {                    // ---- Wu1t [64][128]
        const int i = (b - WT_NB) * 256 + tid;
        const int n = i >> 7, k = i & 127;
        wu[i] = (_Float16)Wu1[k * 64 + n];
    } else {                                           // ---- histogram + rank
        const int e = (b - WT_NB - WU_NB) * 256 + tid;
        rank[e] = atomicAdd(&deg[ei[Ee + e]], 1);
    }
}

// ===========================================================================
// scan1: block-local exclusive scan of deg -> off, per-block totals -> bsum.
// (cross-block prefix folded into fill via a 13-entry LDS prefix)
// ===========================================================================
__global__ __launch_bounds__(1024) void scan1_kernel(const int* __restrict__ deg,
                                                     int* __restrict__ off,
                                                     int* __restrict__ bsum) {
    __shared__ int wsum[16];
    const int tid = threadIdx.x;
    const int lane = tid & 63, wid = tid >> 6;
    const int base = blockIdx.x * SCAN_TILE + tid * 4;

    int v0 = (base + 0 < Nn) ? deg[base + 0] : 0;
    int v1 = (base + 1 < Nn) ? deg[base + 1] : 0;
    int v2 = (base + 2 < Nn) ? deg[base + 2] : 0;
    int v3 = (base + 3 < Nn) ? deg[base + 3] : 0;
    const int tsum = v0 + v1 + v2 + v3;

    int x = tsum;
    for (int s = 1; s < 64; s <<= 1) {
        int y = __shfl_up(x, s, 64);
        if (lane >= s) x += y;
    }
    if (lane == 63) wsum[wid] = x;
    __syncthreads();
    if (wid == 0) {
        int w = (lane < 16) ? wsum[lane] : 0;
        for (int s = 1; s < 16; s <<= 1) {
            int y = __shfl_up(w, s, 64);
            if (lane >= s) w += y;
        }
        if (lane < 16) wsum[lane] = w;
    }
    __syncthreads();
    const int wpre = wid ? wsum[wid - 1] : 0;
    const int tpre = wpre + (x - tsum);
    if (base + 0 < Nn) off[base + 0] = tpre;
    if (base + 1 < Nn) off[base + 1] = tpre + v0;
    if (base + 2 < Nn) off[base + 2] = tpre + v0 + v1;
    if (base + 3 < Nn) off[base + 3] = tpre + v0 + v1 + v2;
    if (tid == 1023) bsum[blockIdx.x] = wsum[15];
}

// ===========================================================================
// MFMA helpers
// ===========================================================================
__device__ __forceinline__ floatx16 mfma16(half8 a, half8 b, floatx16 c) {
    return __builtin_amdgcn_mfma_f32_32x32x16_f16(a, b, c, 0, 0, 0);
}

__device__ __forceinline__ unsigned pkrtz(float a, float b) {
    union { fp16x2 h; unsigned u; } c;
    c.h = __builtin_amdgcn_cvt_pkrtz(a, b);
    return c.u;
}

__device__ __forceinline__ half8 hmax0(half8 v) {
#if __has_builtin(__builtin_elementwise_max)
    half8 z = {};
    return __builtin_elementwise_max(v, z);
#else
    #pragma unroll
    for (int i = 0; i < 8; ++i) v[i] = v[i] > (_Float16)0 ? v[i] : (_Float16)0;
    return v;
#endif
}

// packed-f16 bias+relu epilogue: 8 pkrtz + 4 pk_add + 4 pk_max per half
__device__ __forceinline__ void pack_acc2(const floatx16& acc, half8 bA, half8 bB,
                                          unsigned* pk) {
    union { half8 h; unsigned u[4]; } c0, c1;
    #pragma unroll
    for (int q = 0; q < 4; ++q) c0.u[q] = pkrtz(acc[2 * q], acc[2 * q + 1]);
    #pragma unroll
    for (int q = 0; q < 4; ++q) c1.u[q] = pkrtz(acc[8 + 2 * q], acc[8 + 2 * q + 1]);
    c0.h = hmax0(c0.h + bA);
    c1.h = hmax0(c1.h + bB);
    pk[0] = c0.u[0]; pk[1] = c0.u[1]; pk[2] = c0.u[2]; pk[3] = c0.u[3];
    pk[4] = c1.u[0]; pk[5] = c1.u[1]; pk[6] = c1.u[2]; pk[7] = c1.u[3];
}

__device__ __forceinline__ void pack_acc_nb(const floatx16& acc, unsigned* pk) {
    union { half8 h; unsigned u[4]; } c0, c1;
    #pragma unroll
    for (int q = 0; q < 4; ++q) c0.u[q] = pkrtz(acc[2 * q], acc[2 * q + 1]);
    #pragma unroll
    for (int q = 0; q < 4; ++q) c1.u[q] = pkrtz(acc[8 + 2 * q], acc[8 + 2 * q + 1]);
    c0.h = hmax0(c0.h);
    c1.h = hmax0(c1.h);
    pk[0] = c0.u[0]; pk[1] = c0.u[1]; pk[2] = c0.u[2]; pk[3] = c0.u[3];
    pk[4] = c1.u[0]; pk[5] = c1.u[1]; pk[6] = c1.u[2]; pk[7] = c1.u[3];
}

__device__ __forceinline__ half8 frag_from_pk(const unsigned* pk, int s1, int kh) {
    const unsigned lo0 = pk[4 * s1], lo1 = pk[4 * s1 + 1];
    const unsigned hi0 = pk[4 * s1 + 2], hi1 = pk[4 * s1 + 3];
    const unsigned X0 = kh ? lo0 : hi0;
    const unsigned X1 = kh ? lo1 : hi1;
    const unsigned r0 = (unsigned)__shfl_xor((int)X0, 32, 64);
    const unsigned r1 = (unsigned)__shfl_xor((int)X1, 32, 64);
    union { half8 h; unsigned u[4]; } f;
    f.u[0] = kh ? r0 : lo0;
    f.u[1] = kh ? r1 : lo1;
    f.u[2] = kh ? hi0 : r0;
    f.u[3] = kh ? hi1 : r1;
    return f.h;
}

// ===========================================================================
// Fused fill+pq. Blocks [0,FILL_NB): atomic-free scatter (13-prefix in LDS,
// scan2 launch deleted) + sums zeroing. Blocks [FILL_NB,..): per-node
// P/Q precompute in C-fragment-permuted layout (R12).
// ===========================================================================
__global__ __launch_bounds__(256) void fillpq_kernel(
    const int* __restrict__ ei, const int* __restrict__ off,
    const int* __restrict__ bsum, const int* __restrict__ rank,
    const float* __restrict__ cent,
    int4* __restrict__ sdd, float4* __restrict__ sums4,
    const float* __restrict__ z, const _Float16* __restrict__ wt,
    const float* __restrict__ bm1, _Float16* __restrict__ pq)
{
    const int tid = threadIdx.x;
    if (blockIdx.x < FILL_NB) {
        __shared__ int pb13[SCAN_NBLK];
        if (tid == 0) {
            int acc = 0;
            for (int i = 0; i < SCAN_NBLK; ++i) { pb13[i] = acc; acc += bsum[i]; }
        }
        __syncthreads();

        const int e = blockIdx.x * 256 + tid;
        const int s = ei[e];
        const int d = ei[Ee + e];
        sums4[e] = make_float4(0.f, 0.f, 0.f, 0.f);

        const float d0 = cent[d * 3 + 0] - cent[s * 3 + 0];
        const float d1 = cent[d * 3 + 1] - cent[s * 3 + 1];
        const float d2 = cent[d * 3 + 2] - cent[s * 3 + 2];
        const int p01 = (int)pkrtz(d0, d1);
        const int p2  = (int)pkrtz(d2, 0.0f);

        const int pos = off[d] + pb13[d >> 12] + rank[e];
        sdd[pos] = make_int4(s, d, p01, p2);
        return;
    }

    // ---- pq part ----
    const int wid = tid >> 6, lane = tid & 63;
    const int er = lane & 31, kh = lane >> 5;
    const int tile = ((blockIdx.x - FILL_NB) * 4 + wid) * 32;
    const int nclamp = (tile + er < Nn) ? (tile + er) : (Nn - 1);

    const float* __restrict__ zr = z + (size_t)nclamp * 64;
    half8 a[4];
    #pragma unroll
    for (int s = 0; s < 4; ++s) {
        const int base = s * 16 + kh * 8;
        const float4 u = *(const float4*)(zr + base);
        const float4 v = *(const float4*)(zr + base + 4);
        union { half8 h; unsigned w[4]; } hv;
        hv.w[0] = pkrtz(u.x, u.y);
        hv.w[1] = pkrtz(u.z, u.w);
        hv.w[2] = pkrtz(v.x, v.y);
        hv.w[3] = pkrtz(v.z, v.w);
        a[s] = hv.h;
    }

    const _Float16* __restrict__ wm1t = wt + WM1T;
    floatx16 P0, P1, Q0, Q1;
    const float b0 = bm1[er], b1 = bm1[32 + er];
    #pragma unroll
    for (int r = 0; r < 16; ++r) { P0[r] = b0; P1[r] = b1; Q0[r] = 0.f; Q1[r] = 0.f; }

    #pragma unroll
    for (int s = 0; s < 4; ++s) {
        const half8 wp0 = *(const half8*)(wm1t + er * 192 + s * 16 + kh * 8);
        const half8 wp1 = *(const half8*)(wm1t + (32 + er) * 192 + s * 16 + kh * 8);
        const half8 wq0 = *(const half8*)(wm1t + er * 192 + 64 + s * 16 + kh * 8);
        const half8 wq1 = *(const half8*)(wm1t + (32 + er) * 192 + 64 + s * 16 + kh * 8);
        P0 = mfma16(a[s], wp0, P0);
        P1 = mfma16(a[s], wp1, P1);
        Q0 = mfma16(a[s], wq0, Q0);
        Q1 = mfma16(a[s], wq1, Q1);
    }

    const int kh_t = (er >> 2) & 1;
    const int r_t = (er & 3) + 4 * ((er >> 3) & 3);
    #pragma unroll
    for (int r = 0; r < 16; ++r) {
        const int n = tile + (r & 3) + 8 * (r >> 2) + 4 * kh;
        if (n < Nn) {
            _Float16* row = pq + (size_t)n * 128;
            row[kh_t * 32 + r_t]           = (_Float16)P0[r];
            row[kh_t * 32 + 16 + r_t]      = (_Float16)P1[r];
            row[64 + kh_t * 32 + r_t]      = (_Float16)Q0[r];
            row[64 + kh_t * 32 + 16 + r_t] = (_Float16)Q1[r];
        }
    }
}

// ===========================================================================
// Edge kernel: R13 structure + packed-f16 bias/relu epilogues (bias table
// staged in LDS with the weights).
// ===========================================================================
__global__ __launch_bounds__(512) void edge_mfma_kernel(
    const int4* __restrict__ sdd,
    const _Float16* __restrict__ wt, const _Float16* __restrict__ pq,
    const float* __restrict__ bm2,
    float* __restrict__ sums)
{
    __shared__ _Float16 swt[SWT_HALVES];   // 29952 B
    const int tid = threadIdx.x;
    const int wid = tid >> 6, lane = tid & 63;
    const int er = lane & 31;
    const int kh = lane >> 5;
    const int tile = (blockIdx.x * 8 + wid) * 32;   // 3125*8 = 25000 waves exact

    // ---- stage: We1 | We2 | Wm1c | Wm2 | pbias (1680 16B chunks) ----
    {
        const half8* __restrict__ g = (const half8*)wt;
        for (int i = tid; i < 1680; i += 512) {
            int gidx, dst;
            if (i < 128) {
                gidx = i;                       dst = SWE1 + i * 8;
            } else if (i < 640) {
                const int j = i - 128;
                gidx = 128 + j;                 dst = SWE2 + (j >> 3) * 72 + (j & 7) * 8;
            } else if (i < 1152) {
                const int j = i - 640;
                gidx = (WM1C >> 3) + j;         dst = SWM1C + (j >> 3) * 72 + (j & 7) * 8;
            } else if (i < 1664) {
                const int j = i - 1152;
                gidx = (WM2T >> 3) + j;         dst = SWM2 + (j >> 3) * 72 + (j & 7) * 8;
            } else {
                const int j = i - 1664;
                gidx = (PBIAS >> 3) + j;        dst = SPB + j * 8;
            }
            *(half8*)(swt + dst) = g[gidx];
        }
    }

    const int p = tile + er;
    const int4 ed = sdd[p];          // (src, dst, delta01, delta2_)

    // ---- PQ gathers: P[src] + Q[dst] segments (64B each) ----
    const half8* __restrict__ prow = (const half8*)(pq + (size_t)ed.x * 128 + kh * 32);
    const half8* __restrict__ qrow = (const half8*)(pq + (size_t)ed.y * 128 + 64 + kh * 32);
    const half8 pf0 = prow[0], pf1 = prow[1], pf2 = prow[2], pf3 = prow[3];
    const half8 qf0 = qrow[0], qf1 = qrow[1], qf2 = qrow[2], qf3 = qrow[3];

    __syncthreads();   // weights staged

    const _Float16* __restrict__ pbb = swt + SPB;
    const half8 b1A0 = *(const half8*)(pbb + kh * 16);
    const half8 b1A1 = *(const half8*)(pbb + kh * 16 + 8);
    const half8 b1B0 = *(const half8*)(pbb + 32 + kh * 16);
    const half8 b1B1 = *(const half8*)(pbb + 32 + kh * 16 + 8);
    const half8 b2A0 = *(const half8*)(pbb + 64 + kh * 16);
    const half8 b2A1 = *(const half8*)(pbb + 64 + kh * 16 + 8);
    const half8 b2B0 = *(const half8*)(pbb + 96 + kh * 16);
    const half8 b2B1 = *(const half8*)(pbb + 96 + kh * 16 + 8);

    // ---- e1' = (delta @ We1)^T : K=16 (3 real) ----
    half8 bdel;
    #pragma unroll
    for (int j = 0; j < 8; ++j) bdel[j] = (_Float16)0.0f;
    if (kh == 0) {
        union { int i; _Float16 h[2]; } u01, u2;
        u01.i = ed.z; u2.i = ed.w;
        bdel[0] = u01.h[0]; bdel[1] = u01.h[1]; bdel[2] = u2.h[0];
    }

    unsigned pk0[8], pk1[8];
    {
        floatx16 A0, A1;
        #pragma unroll
        for (int r = 0; r < 16; ++r) { A0[r] = 0.0f; A1[r] = 0.0f; }
        const half8 w0 = *(const half8*)(swt + SWE1 + er * 16 + kh * 8);
        const half8 w1 = *(const half8*)(swt + SWE1 + (32 + er) * 16 + kh * 8);
        A0 = mfma16(w0, bdel, A0);
        A1 = mfma16(w1, bdel, A1);
        pack_acc2(A0, b1A0, b1A1, pk0);
        pack_acc2(A1, b1B0, b1B1, pk1);
    }

    // ---- e2' = (e1 @ We2)^T : K=64 ----
    unsigned qk0[8], qk1[8];
    {
        floatx16 B0, B1;
        #pragma unroll
        for (int r = 0; r < 16; ++r) { B0[r] = 0.0f; B1[r] = 0.0f; }
        #pragma unroll
        for (int s = 0; s < 4; ++s) {
            const half8 act = frag_from_pk((s < 2) ? pk0 : pk1, s & 1, kh);
            const half8 w0 = *(const half8*)(swt + SWE2 + er * 72 + s * 16 + kh * 8);
            const half8 w1 = *(const half8*)(swt + SWE2 + (32 + er) * 72 + s * 16 + kh * 8);
            B0 = mfma16(w0, act, B0);
            B1 = mfma16(w1, act, B1);
        }
        pack_acc2(B0, b2A0, b2A1, qk0);
        pack_acc2(B1, b2B0, b2B1, qk1);
    }

    // ---- h1' : init = P[src]+Q[dst] (bm1 folded in P), + e2 @ Wm1c ----
    unsigned rk0[8], rk1[8];
    {
        floatx16 C0, C1;
        #pragma unroll
        for (int r = 0; r < 8; ++r) {
            C0[r]     = (float)pf0[r] + (float)qf0[r];
            C0[8 + r] = (float)pf1[r] + (float)qf1[r];
            C1[r]     = (float)pf2[r] + (float)qf2[r];
            C1[8 + r] = (float)pf3[r] + (float)qf3[r];
        }
        #pragma unroll
        for (int s = 0; s < 4; ++s) {
            const half8 act = frag_from_pk((s < 2) ? qk0 : qk1, s & 1, kh);
            const half8 w0 = *(const half8*)(swt + SWM1C + er * 72 + s * 16 + kh * 8);
            const half8 w1 = *(const half8*)(swt + SWM1C + (32 + er) * 72 + s * 16 + kh * 8);
            C0 = mfma16(w0, act, C0);
            C1 = mfma16(w1, act, C1);
        }
        pack_acc_nb(C0, rk0);
        pack_acc_nb(C1, rk1);
    }

    // ---- m = h1 @ Wm2 + bm2 : NORMAL orientation (edges in C-rows) ----
    floatx16 M0, M1;
    {
        const float bias0 = bm2[er], bias1 = bm2[32 + er];
        #pragma unroll
        for (int r = 0; r < 16; ++r) { M0[r] = bias0; M1[r] = bias1; }
        #pragma unroll
        for (int s = 0; s < 4; ++s) {
            const half8 act = frag_from_pk((s < 2) ? rk0 : rk1, s & 1, kh);
            const half8 w0 = *(const half8*)(swt + SWM2 + er * 72 + s * 16 + kh * 8);
            const half8 w1 = *(const half8*)(swt + SWM2 + (32 + er) * 72 + s * 16 + kh * 8);
            M0 = mfma16(act, w0, M0);
            M1 = mfma16(act, w1, M1);
        }
    }

    // ---- segmented (by dst) reduction + coalesced atomics ----
    const int dprev = __shfl(ed.y, (er + 31) & 31, 64);
    const bool boundary = (er == 0) || (ed.y != dprev);
    unsigned int m32 = (unsigned int)__ballot(boundary);

    while (m32) {
        const int a = __builtin_ctz(m32);
        m32 &= m32 - 1;
        const int b = m32 ? __builtin_ctz(m32) : 32;
        float p0 = 0.0f, p1 = 0.0f;
        #pragma unroll
        for (int r = 0; r < 16; ++r) {
            const int rrow = (r & 3) + 8 * (r >> 2) + 4 * kh;
            if (rrow >= a && rrow < b) { p0 += M0[r]; p1 += M1[r]; }
        }
        p0 += __shfl_xor(p0, 32, 64);
        p1 += __shfl_xor(p1, 32, 64);
        const float val = kh ? p1 : p0;
        const int dseg = __shfl(ed.y, a, 64);
        atomicAdd(&sums[(size_t)dseg * 64 + lane], val);
    }
}

// ===========================================================================
// Node kernel (MFMA): 512-thread blocks — 8 waves share one Wu staging.
// ===========================================================================
__global__ __launch_bounds__(512) void node_mfma_kernel(
    const float* __restrict__ z, const _Float16* __restrict__ wu1t,
    const float* __restrict__ bu1, const int* __restrict__ deg,
    float* __restrict__ out)
{
    __shared__ _Float16 swu[64 * 136];
    const int tid = threadIdx.x;
    const int wid = tid >> 6, lane = tid & 63;
    const int er = lane & 31, kh = lane >> 5;
    const int tile = (blockIdx.x * 8 + wid) * 32;
    const int node = tile + er;

    {
        const half8* __restrict__ g = (const half8*)wu1t;
        for (int i = tid; i < 1024; i += 512) {
            const half8 v = g[i];
            const int n = i >> 4, c = i & 15;
            *(half8*)(swu + n * 136 + c * 8) = v;
        }
    }

    const int nclamp = (node < Nn) ? node : (Nn - 1);
    const int dn = deg[nclamp];
    const float scale = kh ? (1.0f / fmaxf((float)dn, 1.0f)) : 1.0f;
    const float* __restrict__ rowp = kh ? (out + (size_t)nclamp * 64)
                                        : (z + (size_t)nclamp * 64);
    half8 vreg[8];
    #pragma unroll
    for (int c = 0; c < 8; ++c) {
        const float4 a4 = *(const float4*)(rowp + c * 8);
        const float4 b4 = *(const float4*)(rowp + c * 8 + 4);
        union { half8 h; unsigned u[4]; } hv;
        hv.u[0] = pkrtz(a4.x * scale, a4.y * scale);
        hv.u[1] = pkrtz(a4.z * scale, a4.w * scale);
        hv.u[2] = pkrtz(b4.x * scale, b4.y * scale);
        hv.u[3] = pkrtz(b4.z * scale, b4.w * scale);
        vreg[c] = hv.h;
    }

    __syncthreads();

    floatx16 M0, M1;
    const float bias0 = bu1[er], bias1 = bu1[32 + er];
    #pragma unroll
    for (int r = 0; r < 16; ++r) { M0[r] = bias0; M1[r] = bias1; }
    #pragma unroll
    for (int s = 0; s < 4; ++s) {
        union { half8 h; int i[4]; } u;
        u.h = vreg[2 * s + 1];
        #pragma unroll
        for (int q = 0; q < 4; ++q) u.i[q] = __shfl_xor(u.i[q], 32, 64);
        const half8 act = kh ? u.h : vreg[2 * s];
        const half8 w0 = *(const half8*)(swu + er * 136 + s * 16 + kh * 8);
        const half8 w1 = *(const half8*)(swu + (32 + er) * 136 + s * 16 + kh * 8);
        M0 = mfma16(act, w0, M0);
        M1 = mfma16(act, w1, M1);
    }
    #pragma unroll
    for (int s = 0; s < 4; ++s) {
        union { half8 h; int i[4]; } u;
        u.h = vreg[2 * s];
        #pragma unroll
        for (int q = 0; q < 4; ++q) u.i[q] = __shfl_xor(u.i[q], 32, 64);
        const half8 act = kh ? vreg[2 * s + 1] : u.h;
        const half8 w0 = *(const half8*)(swu + er * 136 + 64 + s * 16 + kh * 8);
        const half8 w1 = *(const half8*)(swu + (32 + er) * 136 + 64 + s * 16 + kh * 8);
        M0 = mfma16(act, w0, M0);
        M1 = mfma16(act, w1, M1);
    }

    #pragma unroll
    for (int r = 0; r < 16; ++r) {
        const int rrow = (r & 3) + 8 * (r >> 2) + 4 * kh;
        const int nrow = tile + rrow;
        if (nrow < Nn) {
            out[(size_t)nrow * 64 + er]      = fmaxf(M0[r], 0.0f);
            out[(size_t)nrow * 64 + 32 + er] = fmaxf(M1[r], 0.0f);
        }
    }
}

// ===========================================================================
// Fallback (atomic, fp32) — only if ws_size too small. Known-correct (R1).
// ===========================================================================
__global__ __launch_bounds__(256) void edge_kernel_atomic(
    const float* __restrict__ z, const float* __restrict__ cent,
    const int* __restrict__ ei,
    const float* __restrict__ We1, const float* __restrict__ be1,
    const float* __restrict__ We2, const float* __restrict__ be2,
    const float* __restrict__ Wm1, const float* __restrict__ bm1,
    const float* __restrict__ Wm2, const float* __restrict__ bm2,
    float* __restrict__ sums, float* __restrict__ cnt)
{
    __shared__ float buf[64][256];
    const int tid = threadIdx.x;
    const int e = blockIdx.x * 256 + tid;
    const int src = ei[e];
    const int dst = ei[Ee + e];
    const float d0 = cent[dst * 3 + 0] - cent[src * 3 + 0];
    const float d1 = cent[dst * 3 + 1] - cent[src * 3 + 1];
    const float d2 = cent[dst * 3 + 2] - cent[src * 3 + 2];
    for (int j = 0; j < 64; ++j) {
        float v = fmaf(d0, We1[j], fmaf(d1, We1[64 + j], fmaf(d2, We1[128 + j], be1[j])));
        buf[j][tid] = fmaxf(v, 0.0f);
    }
    float acc[64];
    #pragma unroll
    for (int j = 0; j < 64; ++j) acc[j] = be2[j];
    for (int k = 0; k < 64; ++k) {
        const float ek = buf[k][tid];
        const float* wrow = We2 + k * 64;
        #pragma unroll
        for (int j = 0; j < 64; ++j) acc[j] = fmaf(ek, wrow[j], acc[j]);
    }
    #pragma unroll
    for (int j = 0; j < 64; ++j) buf[j][tid] = fmaxf(acc[j], 0.0f);
    #pragma unroll
    for (int j = 0; j < 64; ++j) acc[j] = bm1[j];
    const float* zs = z + src * 64;
    for (int k = 0; k < 64; ++k) {
        const float hk = zs[k];
        const float* wrow = Wm1 + k * 64;
        #pragma unroll
        for (int j = 0; j < 64; ++j) acc[j] = fmaf(hk, wrow[j], acc[j]);
    }
    const float* zd = z + dst * 64;
    for (int k = 0; k < 64; ++k) {
        const float hk = zd[k];
        const float* wrow = Wm1 + (64 + k) * 64;
        #pragma unroll
        for (int j = 0; j < 64; ++j) acc[j] = fmaf(hk, wrow[j], acc[j]);
    }
    for (int k = 0; k < 64; ++k) {
        const float hk = buf[k][tid];
        const float* wrow = Wm1 + (128 + k) * 64;
        #pragma unroll
        for (int j = 0; j < 64; ++j) acc[j] = fmaf(hk, wrow[j], acc[j]);
    }
    #pragma unroll
    for (int j = 0; j < 64; ++j) buf[j][tid] = fmaxf(acc[j], 0.0f);
    #pragma unroll
    for (int j = 0; j < 64; ++j) acc[j] = bm2[j];
    for (int k = 0; k < 64; ++k) {
        const float hk = buf[k][tid];
        const float* wrow = Wm2 + k * 64;
        #pragma unroll
        for (int j = 0; j < 64; ++j) acc[j] = fmaf(hk, wrow[j], acc[j]);
    }
    float* srow = sums + dst * 64;
    #pragma unroll
    for (int j = 0; j < 64; ++j) atomicAdd(&srow[j], acc[j]);
    atomicAdd(&cnt[dst], 1.0f);
}

__global__ __launch_bounds__(256) void node_kernel_atomic(
    const float* __restrict__ z,
    const float* __restrict__ Wu1, const float* __restrict__ bu1,
    float* __restrict__ out, const float* __restrict__ cnt)
{
    const int node = (blockIdx.x * 256 + threadIdx.x) >> 6;
    const int j = threadIdx.x & 63;
    const int base = node * 64;
    const float inv = 1.0f / fmaxf(cnt[node], 1.0f);
    const float zj = z[base + j];
    const float mj = out[base + j] * inv;
    float a = bu1[j];
    for (int k = 0; k < 64; ++k)
        a = fmaf(__shfl(zj, k, 64), Wu1[k * 64 + j], a);
    for (int k = 0; k < 64; ++k)
        a = fmaf(__shfl(mj, k, 64), Wu1[(64 + k) * 64 + j], a);
    out[base + j] = fmaxf(a, 0.0f);
}

extern "C" void kernel_launch(void* const* d_in, const int* in_sizes, int n_in,
                              void* d_out, int out_size, void* d_ws, size_t ws_size,
                              hipStream_t stream) {
    const float* z    = (const float*)d_in[0];
    const float* cent = (const float*)d_in[1];
    const int*   ei   = (const int*)d_in[2];
    const float* We1  = (const float*)d_in[3];
    const float* be1  = (const float*)d_in[4];
    const float* We2  = (const float*)d_in[5];
    const float* be2  = (const float*)d_in[6];
    const float* Wm1  = (const float*)d_in[7];
    const float* bm1  = (const float*)d_in[8];
    const float* Wm2  = (const float*)d_in[9];
    const float* bm2  = (const float*)d_in[10];
    const float* Wu1  = (const float*)d_in[11];
    const float* bu1  = (const float*)d_in[12];
    float* out = (float*)d_out;

    if (ws_size >= TOTAL_WS) {
        int4* sdd  = (int4*)((char*)d_ws + SDD_OFF);
        int* deg   = (int*)((char*)d_ws + DEG_OFF);
        int* off   = (int*)((char*)d_ws + OFF_OFF);
        int* bsum  = (int*)((char*)d_ws + BSUM_OFF);
        int* rank  = (int*)((char*)d_ws + RANK_OFF);
        _Float16* wt  = (_Float16*)((char*)d_ws + WT_OFF);
        _Float16* wu  = (_Float16*)((char*)d_ws + WU_OFF);
        _Float16* pq  = (_Float16*)((char*)d_ws + PQ_OFF);

        hipMemsetAsync(deg, 0, Nn * sizeof(int), stream);
        prep_kernel<<<PREP_NB, 256, 0, stream>>>(ei, We1, We2, Wm1, Wm2, Wu1,
                                                 be1, be2, wt, wu, deg, rank);
        scan1_kernel<<<SCAN_NBLK, 1024, 0, stream>>>(deg, off, bsum);
        fillpq_kernel<<<FILLPQ_NB, 256, 0, stream>>>(ei, off, bsum, rank, cent,
                                                     sdd, (float4*)out, z, wt, bm1, pq);
        edge_mfma_kernel<<<Ee / 256, 512, 0, stream>>>(sdd, wt, pq, bm2, out);
        node_mfma_kernel<<<(Nn + 255) / 256, 512, 0, stream>>>(z, wu, bu1, deg, out);
    } else {
        float* cnt = (float*)d_ws;
        hipMemsetAsync(out, 0, (size_t)Nn * 64 * sizeof(float), stream);
        hipMemsetAsync(cnt, 0, (size_t)Nn * sizeof(float), stream);
        edge_kernel_atomic<<<Ee / 256, 256, 0, stream>>>(z, cent, ei,
            We1, be1, We2, be2, Wm1, bm1, Wm2, bm2, out, cnt);
        node_kernel_atomic<<<Nn / 4, 256, 0, stream>>>(z, Wu1, bu1, out, cnt);
    }
}